// Round 2
// baseline (3485.970 us; speedup 1.0000x reference)
//
#include <hip/hip_runtime.h>
#include <hip/hip_fp16.h>

// Problem constants
#define NN 100000
#define NE 1600000
#define DIN 32
#define DE 16
#define HC 64
#define NL 4
#define MHC 128
#define OUTC 10
#define NG 128

typedef _Float16 half2_t __attribute__((ext_vector_type(2)));

__device__ __forceinline__ float dot2f(unsigned pv, half2_t w2, float acc) {
#if __has_builtin(__builtin_amdgcn_fdot2)
  return __builtin_amdgcn_fdot2(__builtin_bit_cast(half2_t, pv), w2, acc, false);
#else
  __half2 h = *(__half2*)&pv; __half2 ww = *(__half2*)&w2;
  return acc + __low2float(h) * __low2float(ww) + __high2float(h) * __high2float(ww);
#endif
}

// ---- CSR build ----
__global__ __launch_bounds__(256) void k_deg(const int* __restrict__ dst, int* __restrict__ deg) {
  int e = blockIdx.x * 256 + threadIdx.x;
  if (e < NE) atomicAdd(&deg[dst[e]], 1);
}

__global__ __launch_bounds__(1024) void k_scan1(const int* __restrict__ deg, int* __restrict__ offs, int* __restrict__ bsum) {
  __shared__ int s[1024];
  int t = threadIdx.x;
  int i = blockIdx.x * 1024 + t;
  int v = (i < NN) ? deg[i] : 0;
  s[t] = v; __syncthreads();
  for (int d = 1; d < 1024; d <<= 1) {
    int x = 0;
    if (t >= d) x = s[t - d];
    __syncthreads();
    if (t >= d) s[t] += x;
    __syncthreads();
  }
  if (i < NN) offs[i] = s[t] - v;
  if (t == 1023) bsum[blockIdx.x] = s[t];
}

__global__ __launch_bounds__(128) void k_scan2(int* __restrict__ bsum, int nb) {
  __shared__ int s[128];
  int t = threadIdx.x;
  int v = (t < nb) ? bsum[t] : 0;
  s[t] = v; __syncthreads();
  for (int d = 1; d < 128; d <<= 1) {
    int x = 0;
    if (t >= d) x = s[t - d];
    __syncthreads();
    if (t >= d) s[t] += x;
    __syncthreads();
  }
  if (t < nb) bsum[t] = s[t] - v;
}

// also builds odeg = (start, deg) int2
__global__ __launch_bounds__(256) void k_scan3(int* __restrict__ offs, const int* __restrict__ bsum,
                                               const int* __restrict__ deg,
                                               int* __restrict__ cur, int2* __restrict__ odeg) {
  int i = blockIdx.x * 256 + threadIdx.x;
  if (i < NN) {
    int o = offs[i] + bsum[i >> 10];
    offs[i] = o;
    cur[i] = o;
    odeg[i] = make_int2(o, deg[i]);
  }
}

__global__ __launch_bounds__(256) void k_fill(const int* __restrict__ src, const int* __restrict__ dst,
                                              int* __restrict__ cur, int* __restrict__ csrc, int* __restrict__ ceid) {
  int e = blockIdx.x * 256 + threadIdx.x;
  if (e < NE) {
    int d = dst[e];
    int pos = atomicAdd(&cur[d], 1);
    csrc[pos] = src[e];
    ceid[pos] = e;
  }
}

// ---- gather-cast: eattr (f32, original order) -> e16 (f16-packed, CSR order) ----
__global__ __launch_bounds__(256) void k_cast(const int* __restrict__ ceid,
                                              const float4* __restrict__ eattr4,
                                              uint4* __restrict__ e16) {
  int p = blockIdx.x * 256 + threadIdx.x;
  if (p >= NE) return;
  int e = ceid[p];
  float4 a0 = eattr4[(size_t)e * 4 + 0];
  float4 a1 = eattr4[(size_t)e * 4 + 1];
  float4 a2 = eattr4[(size_t)e * 4 + 2];
  float4 a3 = eattr4[(size_t)e * 4 + 3];
  __half2 h0 = __floats2half2_rn(a0.x, a0.y), h1 = __floats2half2_rn(a0.z, a0.w);
  __half2 h2 = __floats2half2_rn(a1.x, a1.y), h3 = __floats2half2_rn(a1.z, a1.w);
  __half2 h4 = __floats2half2_rn(a2.x, a2.y), h5 = __floats2half2_rn(a2.z, a2.w);
  __half2 h6 = __floats2half2_rn(a3.x, a3.y), h7 = __floats2half2_rn(a3.z, a3.w);
  uint4 o0 = make_uint4(*(unsigned*)&h0, *(unsigned*)&h1, *(unsigned*)&h2, *(unsigned*)&h3);
  uint4 o1 = make_uint4(*(unsigned*)&h4, *(unsigned*)&h5, *(unsigned*)&h6, *(unsigned*)&h7);
  e16[(size_t)p * 2 + 0] = o0;
  e16[(size_t)p * 2 + 1] = o1;
}

// ---- edge weights -> f16 pairs [4 layers][64 ch][8 dwords] + padded biases [4][64] ----
__global__ __launch_bounds__(256) void k_wprep(const float* __restrict__ l0ew, const float* __restrict__ l0eb,
                                               const float* __restrict__ ew, const float* __restrict__ eb,
                                               unsigned* __restrict__ ewh, float* __restrict__ ebp) {
  int i = blockIdx.x * 256 + threadIdx.x;
  if (i < 2048) {
    int L = i >> 9, r = i & 511;
    int c = r >> 3, t = r & 7;
    float a, b;
    if (L == 0) {
      a = (c < 32) ? l0ew[c * 16 + 2 * t] : 0.f;
      b = (c < 32) ? l0ew[c * 16 + 2 * t + 1] : 0.f;
    } else {
      a = ew[(size_t)(L - 1) * 1024 + c * 16 + 2 * t];
      b = ew[(size_t)(L - 1) * 1024 + c * 16 + 2 * t + 1];
    }
    __half2 h = __floats2half2_rn(a, b);
    ewh[i] = *(unsigned*)&h;
  }
  if (i < 256) {
    int L = i >> 6, c = i & 63;
    ebp[i] = (L == 0) ? ((c < 32) ? l0eb[c] : 0.f) : eb[(size_t)(L - 1) * 64 + c];
  }
}

// ---- graph boundaries (batch sorted) ----
__global__ __launch_bounds__(256) void k_gstart(const int* __restrict__ batch, int* __restrict__ gstart) {
  int i = blockIdx.x * 256 + threadIdx.x;
  if (i >= NN) return;
  int b = batch[i];
  int bp = (i == 0) ? -1 : batch[i - 1];
  for (int g = bp + 1; g <= b; g++) gstart[g] = i;
  if (i == NN - 1)
    for (int g = b + 1; g <= NG; g++) gstart[g] = NN;
}

// ---- w2 transpose: w2t[mat][c1][c2] = w2[mat][c2][c1] ----
__global__ __launch_bounds__(256) void k_tr(const float* __restrict__ l0w2, const float* __restrict__ w2,
                                            float* __restrict__ w2t) {
  int id = blockIdx.x * 256 + threadIdx.x;
  int mat = id >> 12;
  int j = id & 4095;
  int c1 = j >> 6, c2 = j & 63;
  const float* s = (mat == 0) ? l0w2 : (w2 + (size_t)(mat - 1) * 4096);
  w2t[mat * 4096 + j] = s[c2 * 64 + c1];
}

// ---- w1 transpose + pad: w1t[L][k][c1]; layer0 k>=32 zero-padded ----
__global__ __launch_bounds__(256) void k_tr1(const float* __restrict__ l0w1, const float* __restrict__ w1,
                                             float* __restrict__ w1t) {
  int id = blockIdx.x * 256 + threadIdx.x;
  if (id >= 4 * 4096) return;
  int L = id >> 12, j = id & 4095;
  int k = j >> 6, c = j & 63;
  float v;
  if (L == 0) v = (k < 32) ? l0w1[c * 32 + k] : 0.f;
  else v = w1[(size_t)(L - 1) * 4096 + c * 64 + k];
  w1t[id] = v;
}

__global__ __launch_bounds__(256) void k_xpad(const float* __restrict__ x, float* __restrict__ xpad) {
  int i = blockIdx.x * 256 + threadIdx.x;   // over NN*64
  if (i >= NN * 64) return;
  int cc = i & 63;
  xpad[i] = (cc < 32) ? x[(size_t)(i >> 6) * 32 + cc] : 0.f;
}

// ---- edge aggregation: wave per node, lane = channel; CSR-ordered f16 eattr via
//      coalesced block load (8 edges/load) + readlane pairs + fdot2.
//      16 x-gathers prefetched per chunk. Optional fused BN+relu on gathered x. ----
template<bool BN>
__global__ __launch_bounds__(256) void k_edgeH(
    const int* __restrict__ csrc, const int2* __restrict__ odeg,
    const float* __restrict__ xsrc, const float* __restrict__ scp, const float* __restrict__ shp,
    const unsigned* __restrict__ e16,
    const unsigned* __restrict__ ewh, const float* __restrict__ ebf,
    float* __restrict__ hpre)
{
  int gt = blockIdx.x * 256 + threadIdx.x;
  int node = gt >> 6;
  if (node >= NN) return;
  int c = threadIdx.x & 63;
  half2_t wh[8];
  {
    const uint4* wv = (const uint4*)(ewh + (size_t)c * 8);
    uint4 q0 = wv[0], q1 = wv[1];
    wh[0] = __builtin_bit_cast(half2_t, q0.x); wh[1] = __builtin_bit_cast(half2_t, q0.y);
    wh[2] = __builtin_bit_cast(half2_t, q0.z); wh[3] = __builtin_bit_cast(half2_t, q0.w);
    wh[4] = __builtin_bit_cast(half2_t, q1.x); wh[5] = __builtin_bit_cast(half2_t, q1.y);
    wh[6] = __builtin_bit_cast(half2_t, q1.z); wh[7] = __builtin_bit_cast(half2_t, q1.w);
  }
  float bcv = ebf[c];
  float scv = 1.f, shv = 0.f;
  if (BN) { scv = scp[c]; shv = shp[c]; }
  int2 od = odeg[node];
  int start = od.x, n = od.y;
  float acc = 0.f;

  for (int base = 0; base < n; base += 16) {
    int cn = min(16, n - base);
    // src indices for the chunk (lanes 0..cn-1)
    int sidx = 0;
    if (c < cn) sidx = csrc[start + base + c];
    // coalesced f16 eattr block loads: one load = 8 edges (64 dwords); lane c holds dword c
    unsigned ead0 = e16[(size_t)(start + base) * 8 + c];
    unsigned ead1 = 0;
    if (cn > 8) ead1 = e16[(size_t)(start + base + 8) * 8 + c];
    // prefetch all x-gathers for the chunk
    float xv[16];
    #pragma unroll
    for (int u = 0; u < 16; u++) {
      if (u < cn) {
        int s = __shfl(sidx, u);
        xv[u] = xsrc[(size_t)s * 64 + c];
      } else xv[u] = 0.f;
    }
    #pragma unroll
    for (int u = 0; u < 16; u++) {
      if (u >= cn) break;
      unsigned eb_ = (u < 8) ? ead0 : ead1;
      int u2 = u & 7;
      float el = bcv;
      #pragma unroll
      for (int t = 0; t < 8; t++) {
        unsigned pv = (unsigned)__builtin_amdgcn_readlane((int)eb_, u2 * 8 + t);
        el = dot2f(pv, wh[t], el);
      }
      float xs = xv[u];
      if (BN) xs = fmaxf(fmaf(xs, scv, shv), 0.f);
      acc += fmaxf(xs + el, 0.f);
    }
  }

  float xself = xsrc[(size_t)node * 64 + c];
  if (BN) xself = fmaxf(fmaf(xself, scv, shv), 0.f);
  hpre[(size_t)node * 64 + c] = xself + acc;
}

// ---- fused node MLP + BN-stats epilogue, v3: 4-way row split.
//      Block = 256 = 4 waves handles 64 rows. Wave w computes channels
//      [16w,16w+16) for all 64 rows (lane = row). Weight indices are
//      wave-uniform (readfirstlane) -> s_load SGPR operands. Activations in
//      one 64x65 LDS tile (pad -> bank (lane+k)%32, 2-way = free).
//      Grid = 1563 blocks = 6252 waves (~6 waves/SIMD vs 1.5 before). ----
template<int CIN>
__global__ __launch_bounds__(256) void k_mlp(
    const float* __restrict__ hpre,
    const float* __restrict__ w1tf, const float* __restrict__ b1f,
    const float* __restrict__ w2tf, const float* __restrict__ b2v,
    float* __restrict__ h2, float* __restrict__ bnsq)
{
  __shared__ float hl[64 * 65];
  int tid = threadIdx.x;
  int wid = __builtin_amdgcn_readfirstlane(tid >> 6);
  int lane = tid & 63;
  int rbase = blockIdx.x * 64;
  // cooperative coalesced load: thread t -> row t>>2, k-offset (t&3)*16
  {
    int r = tid >> 2, ko = (tid & 3) * 16;
    int rg = rbase + r;
    float4 v0, v1, v2, v3;
    if (rg < NN) {
      const float4* src = (const float4*)(hpre + (size_t)rg * 64 + ko);
      v0 = src[0]; v1 = src[1]; v2 = src[2]; v3 = src[3];
    } else {
      v0 = v1 = v2 = v3 = make_float4(0.f, 0.f, 0.f, 0.f);
    }
    float* d = hl + r * 65 + ko;
    *(float4*)(d + 0) = v0; *(float4*)(d + 4) = v1;
    *(float4*)(d + 8) = v2; *(float4*)(d + 12) = v3;
  }
  __syncthreads();
  int w16 = wid * 16;
  const float* hrow = hl + lane * 65;
  float acc[16];
  {
    const float* bp = b1f + w16;
    #pragma unroll
    for (int j = 0; j < 16; j++) acc[j] = bp[j];
  }
  // stage A: mids[w16+j] = relu(b1 + sum_k w1[w16+j][k] * h[k])
  #pragma unroll
  for (int k0 = 0; k0 < CIN; k0 += 4) {
    float4 hv = *(const float4*)(hrow + k0);
    #pragma unroll
    for (int t = 0; t < 4; t++) {
      const float* wr = w1tf + (k0 + t) * 64 + w16;   // wave-uniform -> s_load
      float hvt = (t == 0) ? hv.x : (t == 1) ? hv.y : (t == 2) ? hv.z : hv.w;
      #pragma unroll
      for (int j = 0; j < 16; j++) acc[j] = fmaf(wr[j], hvt, acc[j]);
    }
  }
  #pragma unroll
  for (int j = 0; j < 16; j++) acc[j] = fmaxf(acc[j], 0.f);
  __syncthreads();
  // write mids into the same tile (columns w16..w16+15)
  {
    float* d = hl + lane * 65 + w16;
    *(float4*)(d + 0)  = make_float4(acc[0], acc[1], acc[2], acc[3]);
    *(float4*)(d + 4)  = make_float4(acc[4], acc[5], acc[6], acc[7]);
    *(float4*)(d + 8)  = make_float4(acc[8], acc[9], acc[10], acc[11]);
    *(float4*)(d + 12) = make_float4(acc[12], acc[13], acc[14], acc[15]);
  }
  __syncthreads();
  // stage B: out[w16+j] = relu(b2 + sum_c1 w2t[c1][w16+j] * mid[c1])
  float out[16];
  {
    const float* bp = b2v + w16;
    #pragma unroll
    for (int j = 0; j < 16; j++) out[j] = bp[j];
  }
  #pragma unroll
  for (int k0 = 0; k0 < 64; k0 += 4) {
    float4 mv = *(const float4*)(hrow + k0);
    #pragma unroll
    for (int t = 0; t < 4; t++) {
      const float* wr = w2tf + (k0 + t) * 64 + w16;   // wave-uniform -> s_load
      float mvt = (t == 0) ? mv.x : (t == 1) ? mv.y : (t == 2) ? mv.z : mv.w;
      #pragma unroll
      for (int j = 0; j < 16; j++) out[j] = fmaf(wr[j], mvt, out[j]);
    }
  }
  bool act = (rbase + lane) < NN;
  #pragma unroll
  for (int j = 0; j < 16; j++) out[j] = act ? fmaxf(out[j], 0.f) : 0.f;
  if (act) {
    float4* dst = (float4*)(h2 + (size_t)(rbase + lane) * 64 + w16);
    dst[0] = make_float4(out[0], out[1], out[2], out[3]);
    dst[1] = make_float4(out[4], out[5], out[6], out[7]);
    dst[2] = make_float4(out[8], out[9], out[10], out[11]);
    dst[3] = make_float4(out[12], out[13], out[14], out[15]);
  }
  // BN partial stats: rows live one-per-lane -> wave reduce, lane0 atomics
  #pragma unroll
  for (int j = 0; j < 16; j++) {
    float s = out[j], q = s * s;
    #pragma unroll
    for (int m = 1; m < 64; m <<= 1) { s += __shfl_xor(s, m); q += __shfl_xor(q, m); }
    if (lane == 0) {
      atomicAdd(&bnsq[w16 + j], s);
      atomicAdd(&bnsq[64 + w16 + j], q);
    }
  }
}

__global__ __launch_bounds__(64) void k_bnfin(const float* __restrict__ bnsq,
                                              const float* __restrict__ gamma, const float* __restrict__ beta,
                                              int layer, float* __restrict__ scs, float* __restrict__ shs) {
  int c = threadIdx.x;
  if (c >= 64) return;
  const float* sl = bnsq + layer * 128;
  float mu = sl[c] * (1.0f / NN);
  float var = sl[64 + c] * (1.0f / NN) - mu * mu;
  float r = rsqrtf(var + 1e-5f);
  float s = gamma[layer * 64 + c] * r;
  scs[layer * 64 + c] = s;
  shs[layer * 64 + c] = beta[layer * 64 + c] - mu * s;
}

// ---- pool: BN+relu on the fly; batch sorted -> contiguous ranges ----
__global__ __launch_bounds__(256) void k_pool2(const float* __restrict__ h2, const float* __restrict__ sc,
                                               const float* __restrict__ sh, const int* __restrict__ gstart,
                                               float* __restrict__ pooled) {
  int g = blockIdx.x >> 2, sub = blockIdx.x & 3;
  int s = gstart[g], e = gstart[g + 1];
  int c = threadIdx.x & 63, rg = threadIdx.x >> 6;
  float scv = sc[c], shv = sh[c];
  float acc = 0.f;
  for (int r = s + sub * 4 + rg; r < e; r += 16)
    acc += fmaxf(fmaf(h2[(size_t)r * 64 + c], scv, shv), 0.f);
  __shared__ float ls[256];
  ls[threadIdx.x] = acc;
  __syncthreads();
  if (rg == 0) {
    float v = ls[c] + ls[64 + c] + ls[128 + c] + ls[192 + c];
    atomicAdd(&pooled[g * 64 + c], v);
  }
}

__global__ __launch_bounds__(128) void k_head(const float* __restrict__ pooled, const int* __restrict__ gstart,
                                              const float* __restrict__ hw1, const float* __restrict__ hb1,
                                              const float* __restrict__ hw2, const float* __restrict__ hb2,
                                              float* __restrict__ out) {
  __shared__ float p[64];
  __shared__ float z[128];
  int g = blockIdx.x, t = threadIdx.x;
  if (t < 64) {
    int cn = gstart[g + 1] - gstart[g];
    float inv = 1.0f / (float)(cn > 0 ? cn : 1);
    p[t] = pooled[g * 64 + t] * inv;
  }
  __syncthreads();
  float a = hb1[t];
  #pragma unroll
  for (int k = 0; k < 64; k++) a = fmaf(hw1[t * 64 + k], p[k], a);
  z[t] = fmaxf(a, 0.f);
  __syncthreads();
  if (t < OUTC) {
    float b = hb2[t];
    #pragma unroll
    for (int k = 0; k < 128; k++) b = fmaf(hw2[t * 128 + k], z[k], b);
    out[g * OUTC + t] = b;
  }
}

extern "C" void kernel_launch(void* const* d_in, const int* in_sizes, int n_in,
                              void* d_out, int out_size, void* d_ws, size_t ws_size,
                              hipStream_t stream) {
  const float* x_f   = (const float*)d_in[0];
  const int*   ei    = (const int*)d_in[1];
  const float* eattr = (const float*)d_in[2];
  const int*   batch = (const int*)d_in[3];
  const float* l0_ew = (const float*)d_in[4];
  const float* l0_eb = (const float*)d_in[5];
  const float* l0_w1 = (const float*)d_in[6];
  const float* l0_b1 = (const float*)d_in[7];
  const float* l0_w2 = (const float*)d_in[8];
  const float* l0_b2 = (const float*)d_in[9];
  const float* ew    = (const float*)d_in[10];
  const float* eb    = (const float*)d_in[11];
  const float* w1    = (const float*)d_in[12];
  const float* b1    = (const float*)d_in[13];
  const float* w2    = (const float*)d_in[14];
  const float* b2    = (const float*)d_in[15];
  const float* bng   = (const float*)d_in[16];
  const float* bnb   = (const float*)d_in[17];
  const float* hw1   = (const float*)d_in[18];
  const float* hb1   = (const float*)d_in[19];
  const float* hw2   = (const float*)d_in[20];
  const float* hb2   = (const float*)d_in[21];
  const int* esrc = ei;
  const int* edst = ei + NE;

  char* wsb = (char*)d_ws;
  size_t off = 0;
  auto A = [&](size_t bytes) -> void* {
    void* p = wsb + off;
    off = (off + bytes + 255) & ~(size_t)255;
    return p;
  };
  int*   csrc = (int*)A((size_t)NE * 4);
  int*   ceid = (int*)A((size_t)NE * 4);
  int*   offs = (int*)A((size_t)NN * 4);
  int*   deg  = (int*)A((size_t)NN * 4);
  int*   cur  = (int*)A((size_t)NN * 4);
  int2*  odeg = (int2*)A((size_t)NN * 8);
  int*   bsum = (int*)A(128 * 4);
  int*   gst  = (int*)A((NG + 1) * 4);
  float* xpad = (float*)A((size_t)NN * 64 * 4);
  float* hpre = (float*)A((size_t)NN * 64 * 4);
  float* h2   = (float*)A((size_t)NN * 64 * 4);
  float* bnsq = (float*)A(4 * 128 * 4);   // [layer][sum64|sq64]
  float* scs  = (float*)A(4 * 64 * 4);
  float* shs  = (float*)A(4 * 64 * 4);
  float* pooled = (float*)A((size_t)NG * 64 * 4);
  float* w2t  = (float*)A(4 * 4096 * 4);
  float* w1t  = (float*)A(4 * 4096 * 4);
  unsigned* ewh = (unsigned*)A(2048 * 4);   // f16-pair edge weights, 4 layers
  float* ebp  = (float*)A(256 * 4);         // padded edge biases, 4 layers
  unsigned* e16 = (unsigned*)A(((size_t)NE + 16) * 32);  // f16 eattr, CSR order, 8 dwords/edge

  hipMemsetAsync(deg, 0, (size_t)NN * 4, stream);
  hipMemsetAsync(bnsq, 0, 4 * 128 * 4, stream);
  hipMemsetAsync(pooled, 0, (size_t)NG * 64 * 4, stream);

  k_tr<<<64, 256, 0, stream>>>(l0_w2, w2, w2t);
  k_tr1<<<64, 256, 0, stream>>>(l0_w1, w1, w1t);
  k_wprep<<<8, 256, 0, stream>>>(l0_ew, l0_eb, ew, eb, ewh, ebp);
  k_xpad<<<(NN * 64 + 255) / 256, 256, 0, stream>>>(x_f, xpad);
  k_gstart<<<(NN + 255) / 256, 256, 0, stream>>>(batch, gst);

  k_deg<<<(NE + 255) / 256, 256, 0, stream>>>(edst, deg);
  k_scan1<<<98, 1024, 0, stream>>>(deg, offs, bsum);
  k_scan2<<<1, 128, 0, stream>>>(bsum, 98);
  k_scan3<<<(NN + 255) / 256, 256, 0, stream>>>(offs, bsum, deg, cur, odeg);
  k_fill<<<(NE + 255) / 256, 256, 0, stream>>>(esrc, edst, cur, csrc, ceid);
  k_cast<<<(NE + 255) / 256, 256, 0, stream>>>(ceid, (const float4*)eattr, (uint4*)e16);

  const int nodeBlocks = (NN * 64 + 255) / 256;
  const int rowBlocks = (NN + 63) / 64;

  // ---- layer 0 (padded to C=64; BN=false) ----
  k_edgeH<false><<<nodeBlocks, 256, 0, stream>>>(csrc, odeg, xpad, nullptr, nullptr,
                                                 e16, ewh, ebp, hpre);
  k_mlp<32><<<rowBlocks, 256, 0, stream>>>(hpre, w1t, l0_b1, w2t, l0_b2, h2, bnsq + 0);
  k_bnfin<<<1, 64, 0, stream>>>(bnsq, bng, bnb, 0, scs, shs);

  // ---- layers 1..3: gather from h2 with fused BN(prev)+relu ----
  for (int i = 0; i < 3; i++) {
    k_edgeH<true><<<nodeBlocks, 256, 0, stream>>>(csrc, odeg, h2,
                                                  scs + i * 64, shs + i * 64,
                                                  e16, ewh + (size_t)(i + 1) * 512, ebp + (i + 1) * 64, hpre);
    k_mlp<64><<<rowBlocks, 256, 0, stream>>>(hpre, w1t + (size_t)(i + 1) * 4096, b1 + (size_t)i * 64,
                                             w2t + (size_t)(i + 1) * 4096, b2 + (size_t)i * 64,
                                             h2, bnsq + (i + 1) * 128);
    k_bnfin<<<1, 64, 0, stream>>>(bnsq, bng, bnb, i + 1, scs, shs);
  }

  // ---- pool (applies BN layer 3) + head ----
  k_pool2<<<NG * 4, 256, 0, stream>>>(h2, scs + 3 * 64, shs + 3 * 64, gst, pooled);
  k_head<<<NG, 128, 0, stream>>>(pooled, gst, hw1, hb1, hw2, hb2, (float*)d_out);
}

// Round 3
// 1296.929 us; speedup vs baseline: 2.6879x; 2.6879x over previous
//
#include <hip/hip_runtime.h>
#include <hip/hip_fp16.h>

// Problem constants
#define NN 100000
#define NE 1600000
#define DIN 32
#define DE 16
#define HC 64
#define NL 4
#define MHC 128
#define OUTC 10
#define NG 128

typedef _Float16 half2_t __attribute__((ext_vector_type(2)));

__device__ __forceinline__ float dot2f(unsigned pv, half2_t w2, float acc) {
#if __has_builtin(__builtin_amdgcn_fdot2)
  return __builtin_amdgcn_fdot2(__builtin_bit_cast(half2_t, pv), w2, acc, false);
#else
  __half2 h = *(__half2*)&pv; __half2 ww = *(__half2*)&w2;
  return acc + __low2float(h) * __low2float(ww) + __high2float(h) * __high2float(ww);
#endif
}

// ---- CSR build ----
__global__ __launch_bounds__(256) void k_deg(const int* __restrict__ dst, int* __restrict__ deg) {
  int e = blockIdx.x * 256 + threadIdx.x;
  if (e < NE) atomicAdd(&deg[dst[e]], 1);
}

__global__ __launch_bounds__(1024) void k_scan1(const int* __restrict__ deg, int* __restrict__ offs, int* __restrict__ bsum) {
  __shared__ int s[1024];
  int t = threadIdx.x;
  int i = blockIdx.x * 1024 + t;
  int v = (i < NN) ? deg[i] : 0;
  s[t] = v; __syncthreads();
  for (int d = 1; d < 1024; d <<= 1) {
    int x = 0;
    if (t >= d) x = s[t - d];
    __syncthreads();
    if (t >= d) s[t] += x;
    __syncthreads();
  }
  if (i < NN) offs[i] = s[t] - v;
  if (t == 1023) bsum[blockIdx.x] = s[t];
}

__global__ __launch_bounds__(128) void k_scan2(int* __restrict__ bsum, int nb) {
  __shared__ int s[128];
  int t = threadIdx.x;
  int v = (t < nb) ? bsum[t] : 0;
  s[t] = v; __syncthreads();
  for (int d = 1; d < 128; d <<= 1) {
    int x = 0;
    if (t >= d) x = s[t - d];
    __syncthreads();
    if (t >= d) s[t] += x;
    __syncthreads();
  }
  if (t < nb) bsum[t] = s[t] - v;
}

// also builds odeg = (start, deg) int2
__global__ __launch_bounds__(256) void k_scan3(int* __restrict__ offs, const int* __restrict__ bsum,
                                               const int* __restrict__ deg,
                                               int* __restrict__ cur, int2* __restrict__ odeg) {
  int i = blockIdx.x * 256 + threadIdx.x;
  if (i < NN) {
    int o = offs[i] + bsum[i >> 10];
    offs[i] = o;
    cur[i] = o;
    odeg[i] = make_int2(o, deg[i]);
  }
}

__global__ __launch_bounds__(256) void k_fill(const int* __restrict__ src, const int* __restrict__ dst,
                                              int* __restrict__ cur, int* __restrict__ csrc, int* __restrict__ ceid) {
  int e = blockIdx.x * 256 + threadIdx.x;
  if (e < NE) {
    int d = dst[e];
    int pos = atomicAdd(&cur[d], 1);
    csrc[pos] = src[e];
    ceid[pos] = e;
  }
}

// ---- gather-cast: eattr (f32, original order) -> e16 (f16-packed, CSR order) ----
__global__ __launch_bounds__(256) void k_cast(const int* __restrict__ ceid,
                                              const float4* __restrict__ eattr4,
                                              uint4* __restrict__ e16) {
  int p = blockIdx.x * 256 + threadIdx.x;
  if (p >= NE) return;
  int e = ceid[p];
  float4 a0 = eattr4[(size_t)e * 4 + 0];
  float4 a1 = eattr4[(size_t)e * 4 + 1];
  float4 a2 = eattr4[(size_t)e * 4 + 2];
  float4 a3 = eattr4[(size_t)e * 4 + 3];
  __half2 h0 = __floats2half2_rn(a0.x, a0.y), h1 = __floats2half2_rn(a0.z, a0.w);
  __half2 h2 = __floats2half2_rn(a1.x, a1.y), h3 = __floats2half2_rn(a1.z, a1.w);
  __half2 h4 = __floats2half2_rn(a2.x, a2.y), h5 = __floats2half2_rn(a2.z, a2.w);
  __half2 h6 = __floats2half2_rn(a3.x, a3.y), h7 = __floats2half2_rn(a3.z, a3.w);
  uint4 o0 = make_uint4(*(unsigned*)&h0, *(unsigned*)&h1, *(unsigned*)&h2, *(unsigned*)&h3);
  uint4 o1 = make_uint4(*(unsigned*)&h4, *(unsigned*)&h5, *(unsigned*)&h6, *(unsigned*)&h7);
  e16[(size_t)p * 2 + 0] = o0;
  e16[(size_t)p * 2 + 1] = o1;
}

// ---- edge weights -> f16 pairs [4 layers][64 ch][8 dwords] + padded biases [4][64] ----
__global__ __launch_bounds__(256) void k_wprep(const float* __restrict__ l0ew, const float* __restrict__ l0eb,
                                               const float* __restrict__ ew, const float* __restrict__ eb,
                                               unsigned* __restrict__ ewh, float* __restrict__ ebp) {
  int i = blockIdx.x * 256 + threadIdx.x;
  if (i < 2048) {
    int L = i >> 9, r = i & 511;
    int c = r >> 3, t = r & 7;
    float a, b;
    if (L == 0) {
      a = (c < 32) ? l0ew[c * 16 + 2 * t] : 0.f;
      b = (c < 32) ? l0ew[c * 16 + 2 * t + 1] : 0.f;
    } else {
      a = ew[(size_t)(L - 1) * 1024 + c * 16 + 2 * t];
      b = ew[(size_t)(L - 1) * 1024 + c * 16 + 2 * t + 1];
    }
    __half2 h = __floats2half2_rn(a, b);
    ewh[i] = *(unsigned*)&h;
  }
  if (i < 256) {
    int L = i >> 6, c = i & 63;
    ebp[i] = (L == 0) ? ((c < 32) ? l0eb[c] : 0.f) : eb[(size_t)(L - 1) * 64 + c];
  }
}

// ---- graph boundaries (batch sorted) ----
__global__ __launch_bounds__(256) void k_gstart(const int* __restrict__ batch, int* __restrict__ gstart) {
  int i = blockIdx.x * 256 + threadIdx.x;
  if (i >= NN) return;
  int b = batch[i];
  int bp = (i == 0) ? -1 : batch[i - 1];
  for (int g = bp + 1; g <= b; g++) gstart[g] = i;
  if (i == NN - 1)
    for (int g = b + 1; g <= NG; g++) gstart[g] = NN;
}

// ---- w2 transpose: w2t[mat][c1][c2] = w2[mat][c2][c1] ----
__global__ __launch_bounds__(256) void k_tr(const float* __restrict__ l0w2, const float* __restrict__ w2,
                                            float* __restrict__ w2t) {
  int id = blockIdx.x * 256 + threadIdx.x;
  int mat = id >> 12;
  int j = id & 4095;
  int c1 = j >> 6, c2 = j & 63;
  const float* s = (mat == 0) ? l0w2 : (w2 + (size_t)(mat - 1) * 4096);
  w2t[mat * 4096 + j] = s[c2 * 64 + c1];
}

// ---- w1 transpose + pad: w1t[L][k][c1]; layer0 k>=32 zero-padded ----
__global__ __launch_bounds__(256) void k_tr1(const float* __restrict__ l0w1, const float* __restrict__ w1,
                                             float* __restrict__ w1t) {
  int id = blockIdx.x * 256 + threadIdx.x;
  if (id >= 4 * 4096) return;
  int L = id >> 12, j = id & 4095;
  int k = j >> 6, c = j & 63;
  float v;
  if (L == 0) v = (k < 32) ? l0w1[c * 32 + k] : 0.f;
  else v = w1[(size_t)(L - 1) * 4096 + c * 64 + k];
  w1t[id] = v;
}

__global__ __launch_bounds__(256) void k_xpad(const float* __restrict__ x, float* __restrict__ xpad) {
  int i = blockIdx.x * 256 + threadIdx.x;   // over NN*64
  if (i >= NN * 64) return;
  int cc = i & 63;
  xpad[i] = (cc < 32) ? x[(size_t)(i >> 6) * 32 + cc] : 0.f;
}

// ---- edge aggregation: wave per node, lane = channel; CSR-ordered f16 eattr via
//      coalesced block load (8 edges/load) + readlane pairs + fdot2.
//      16 x-gathers prefetched per chunk. Optional fused BN+relu on gathered x. ----
template<bool BN>
__global__ __launch_bounds__(256) void k_edgeH(
    const int* __restrict__ csrc, const int2* __restrict__ odeg,
    const float* __restrict__ xsrc, const float* __restrict__ scp, const float* __restrict__ shp,
    const unsigned* __restrict__ e16,
    const unsigned* __restrict__ ewh, const float* __restrict__ ebf,
    float* __restrict__ hpre)
{
  int gt = blockIdx.x * 256 + threadIdx.x;
  int node = gt >> 6;
  if (node >= NN) return;
  int c = threadIdx.x & 63;
  half2_t wh[8];
  {
    const uint4* wv = (const uint4*)(ewh + (size_t)c * 8);
    uint4 q0 = wv[0], q1 = wv[1];
    wh[0] = __builtin_bit_cast(half2_t, q0.x); wh[1] = __builtin_bit_cast(half2_t, q0.y);
    wh[2] = __builtin_bit_cast(half2_t, q0.z); wh[3] = __builtin_bit_cast(half2_t, q0.w);
    wh[4] = __builtin_bit_cast(half2_t, q1.x); wh[5] = __builtin_bit_cast(half2_t, q1.y);
    wh[6] = __builtin_bit_cast(half2_t, q1.z); wh[7] = __builtin_bit_cast(half2_t, q1.w);
  }
  float bcv = ebf[c];
  float scv = 1.f, shv = 0.f;
  if (BN) { scv = scp[c]; shv = shp[c]; }
  int2 od = odeg[node];
  int start = od.x, n = od.y;
  float acc = 0.f;

  for (int base = 0; base < n; base += 16) {
    int cn = min(16, n - base);
    // src indices for the chunk (lanes 0..cn-1)
    int sidx = 0;
    if (c < cn) sidx = csrc[start + base + c];
    // coalesced f16 eattr block loads: one load = 8 edges (64 dwords); lane c holds dword c
    unsigned ead0 = e16[(size_t)(start + base) * 8 + c];
    unsigned ead1 = 0;
    if (cn > 8) ead1 = e16[(size_t)(start + base + 8) * 8 + c];
    // prefetch all x-gathers for the chunk
    float xv[16];
    #pragma unroll
    for (int u = 0; u < 16; u++) {
      if (u < cn) {
        int s = __shfl(sidx, u);
        xv[u] = xsrc[(size_t)s * 64 + c];
      } else xv[u] = 0.f;
    }
    #pragma unroll
    for (int u = 0; u < 16; u++) {
      if (u >= cn) break;
      unsigned eb_ = (u < 8) ? ead0 : ead1;
      int u2 = u & 7;
      float el = bcv;
      #pragma unroll
      for (int t = 0; t < 8; t++) {
        unsigned pv = (unsigned)__builtin_amdgcn_readlane((int)eb_, u2 * 8 + t);
        el = dot2f(pv, wh[t], el);
      }
      float xs = xv[u];
      if (BN) xs = fmaxf(fmaf(xs, scv, shv), 0.f);
      acc += fmaxf(xs + el, 0.f);
    }
  }

  float xself = xsrc[(size_t)node * 64 + c];
  if (BN) xself = fmaxf(fmaf(xself, scv, shv), 0.f);
  hpre[(size_t)node * 64 + c] = xself + acc;
}

// ---- fused node MLP + BN-stats epilogue, v4: weights staged in LDS.
//      R2 lesson: wave-uniform GLOBAL weight addresses scalarize to s_load ->
//      scalar-cache BW (~330 GB/s device) is the bottleneck. Fix: stage the
//      16KB weight matrix in LDS; wave-uniform LDS reads broadcast for free.
//      Block = 256 = 4 waves over 64 rows; wave w owns channels [16w,16w+16),
//      lane = row. One weight buffer reused for w1 then w2 (w2 global loads
//      issued before stage A, LDS-written after the stage-A sync).
//      BN atomics split over 32 copies to kill contention. ----
template<int CIN>
__global__ __launch_bounds__(256) void k_mlp(
    const float* __restrict__ hpre,
    const float* __restrict__ w1tf, const float* __restrict__ b1f,
    const float* __restrict__ w2tf, const float* __restrict__ b2v,
    float* __restrict__ h2, float* __restrict__ bnsq)
{
  __shared__ float wl[64 * 64];   // weight tile (16KB), w1 then w2
  __shared__ float hl[64 * 65];   // act tile, pad 65 -> 2-way bank = free
  int tid = threadIdx.x;
  int wid = __builtin_amdgcn_readfirstlane(tid >> 6);
  int lane = tid & 63;
  int rbase = blockIdx.x * 64;
  // stage w1 -> LDS (coalesced: wave reads 1KB contiguous)
  {
    const float4* s = (const float4*)w1tf;
    float4* d = (float4*)wl;
    #pragma unroll
    for (int q = 0; q < 4; q++) d[tid + 256 * q] = s[tid + 256 * q];
  }
  // stage act tile: thread t -> row t>>2, k-offset (t&3)*16
  {
    int r = tid >> 2, ko = (tid & 3) * 16;
    int rg = rbase + r;
    float4 v0, v1, v2, v3;
    if (rg < NN) {
      const float4* src = (const float4*)(hpre + (size_t)rg * 64 + ko);
      v0 = src[0]; v1 = src[1]; v2 = src[2]; v3 = src[3];
    } else {
      v0 = v1 = v2 = v3 = make_float4(0.f, 0.f, 0.f, 0.f);
    }
    float* d = hl + r * 65 + ko;
    *(float4*)(d + 0) = v0; *(float4*)(d + 4) = v1;
    *(float4*)(d + 8) = v2; *(float4*)(d + 12) = v3;
  }
  // issue w2 global loads early (written to LDS after stage-A sync)
  float4 w2r[4];
  {
    const float4* s = (const float4*)w2tf;
    #pragma unroll
    for (int q = 0; q < 4; q++) w2r[q] = s[tid + 256 * q];
  }
  __syncthreads();
  int w16 = wid * 16;
  const float* hrow = hl + lane * 65;
  // preload this row's activations into registers
  float hreg[CIN];
  #pragma unroll
  for (int k0 = 0; k0 < CIN; k0 += 4) {
    float4 v = *(const float4*)(hrow + k0);
    hreg[k0] = v.x; hreg[k0+1] = v.y; hreg[k0+2] = v.z; hreg[k0+3] = v.w;
  }
  // stage A: mids[w16+j] = relu(b1 + sum_k w1t[k][w16+j] * h[k])
  float acc[16];
  #pragma unroll
  for (int j = 0; j < 16; j++) acc[j] = b1f[w16 + j];
  #pragma unroll
  for (int k = 0; k < CIN; k++) {
    const float* wr = wl + k * 64 + w16;   // wave-uniform LDS -> broadcast
    float hv = hreg[k];
    #pragma unroll
    for (int j = 0; j < 16; j++) acc[j] = fmaf(wr[j], hv, acc[j]);
  }
  #pragma unroll
  for (int j = 0; j < 16; j++) acc[j] = fmaxf(acc[j], 0.f);
  __syncthreads();   // all reads of wl (w1) and hl (h) done
  // write w2 into weight tile; write mids into act tile
  {
    float4* d = (float4*)wl;
    #pragma unroll
    for (int q = 0; q < 4; q++) d[tid + 256 * q] = w2r[q];
  }
  {
    float* d = hl + lane * 65 + w16;
    *(float4*)(d + 0)  = make_float4(acc[0], acc[1], acc[2], acc[3]);
    *(float4*)(d + 4)  = make_float4(acc[4], acc[5], acc[6], acc[7]);
    *(float4*)(d + 8)  = make_float4(acc[8], acc[9], acc[10], acc[11]);
    *(float4*)(d + 12) = make_float4(acc[12], acc[13], acc[14], acc[15]);
  }
  __syncthreads();
  // preload mids
  float mreg[64];
  #pragma unroll
  for (int k0 = 0; k0 < 64; k0 += 4) {
    float4 v = *(const float4*)(hrow + k0);
    mreg[k0] = v.x; mreg[k0+1] = v.y; mreg[k0+2] = v.z; mreg[k0+3] = v.w;
  }
  // stage B: out[w16+j] = relu(b2 + sum_c1 w2t[c1][w16+j] * mid[c1])
  float out[16];
  #pragma unroll
  for (int j = 0; j < 16; j++) out[j] = b2v[w16 + j];
  #pragma unroll
  for (int k = 0; k < 64; k++) {
    const float* wr = wl + k * 64 + w16;   // broadcast
    float mv = mreg[k];
    #pragma unroll
    for (int j = 0; j < 16; j++) out[j] = fmaf(wr[j], mv, out[j]);
  }
  bool act = (rbase + lane) < NN;
  #pragma unroll
  for (int j = 0; j < 16; j++) out[j] = act ? fmaxf(out[j], 0.f) : 0.f;
  if (act) {
    float4* dst = (float4*)(h2 + (size_t)(rbase + lane) * 64 + w16);
    dst[0] = make_float4(out[0], out[1], out[2], out[3]);
    dst[1] = make_float4(out[4], out[5], out[6], out[7]);
    dst[2] = make_float4(out[8], out[9], out[10], out[11]);
    dst[3] = make_float4(out[12], out[13], out[14], out[15]);
  }
  // BN partial stats: wave reduce over rows (lanes), lane0 atomics to 1-of-32 copies
  int cp = (blockIdx.x & 31) * 128;
  #pragma unroll
  for (int j = 0; j < 16; j++) {
    float s = out[j], q = s * s;
    #pragma unroll
    for (int m = 1; m < 64; m <<= 1) { s += __shfl_xor(s, m); q += __shfl_xor(q, m); }
    if (lane == 0) {
      atomicAdd(&bnsq[cp + w16 + j], s);
      atomicAdd(&bnsq[cp + 64 + w16 + j], q);
    }
  }
}

__global__ __launch_bounds__(64) void k_bnfin(const float* __restrict__ bnsq,
                                              const float* __restrict__ gamma, const float* __restrict__ beta,
                                              int layer, float* __restrict__ scs, float* __restrict__ shs) {
  int c = threadIdx.x;
  if (c >= 64) return;
  const float* sl = bnsq + (size_t)layer * 4096;
  float s = 0.f, q = 0.f;
  for (int cp = 0; cp < 32; cp++) { s += sl[cp * 128 + c]; q += sl[cp * 128 + 64 + c]; }
  float mu = s * (1.0f / NN);
  float var = q * (1.0f / NN) - mu * mu;
  float r = rsqrtf(var + 1e-5f);
  float g = gamma[layer * 64 + c] * r;
  scs[layer * 64 + c] = g;
  shs[layer * 64 + c] = beta[layer * 64 + c] - mu * g;
}

// ---- pool: BN+relu on the fly; batch sorted -> contiguous ranges ----
__global__ __launch_bounds__(256) void k_pool2(const float* __restrict__ h2, const float* __restrict__ sc,
                                               const float* __restrict__ sh, const int* __restrict__ gstart,
                                               float* __restrict__ pooled) {
  int g = blockIdx.x >> 2, sub = blockIdx.x & 3;
  int s = gstart[g], e = gstart[g + 1];
  int c = threadIdx.x & 63, rg = threadIdx.x >> 6;
  float scv = sc[c], shv = sh[c];
  float acc = 0.f;
  for (int r = s + sub * 4 + rg; r < e; r += 16)
    acc += fmaxf(fmaf(h2[(size_t)r * 64 + c], scv, shv), 0.f);
  __shared__ float ls[256];
  ls[threadIdx.x] = acc;
  __syncthreads();
  if (rg == 0) {
    float v = ls[c] + ls[64 + c] + ls[128 + c] + ls[192 + c];
    atomicAdd(&pooled[g * 64 + c], v);
  }
}

__global__ __launch_bounds__(128) void k_head(const float* __restrict__ pooled, const int* __restrict__ gstart,
                                              const float* __restrict__ hw1, const float* __restrict__ hb1,
                                              const float* __restrict__ hw2, const float* __restrict__ hb2,
                                              float* __restrict__ out) {
  __shared__ float p[64];
  __shared__ float z[128];
  int g = blockIdx.x, t = threadIdx.x;
  if (t < 64) {
    int cn = gstart[g + 1] - gstart[g];
    float inv = 1.0f / (float)(cn > 0 ? cn : 1);
    p[t] = pooled[g * 64 + t] * inv;
  }
  __syncthreads();
  float a = hb1[t];
  #pragma unroll
  for (int k = 0; k < 64; k++) a = fmaf(hw1[t * 64 + k], p[k], a);
  z[t] = fmaxf(a, 0.f);
  __syncthreads();
  if (t < OUTC) {
    float b = hb2[t];
    #pragma unroll
    for (int k = 0; k < 128; k++) b = fmaf(hw2[t * 128 + k], z[k], b);
    out[g * OUTC + t] = b;
  }
}

extern "C" void kernel_launch(void* const* d_in, const int* in_sizes, int n_in,
                              void* d_out, int out_size, void* d_ws, size_t ws_size,
                              hipStream_t stream) {
  const float* x_f   = (const float*)d_in[0];
  const int*   ei    = (const int*)d_in[1];
  const float* eattr = (const float*)d_in[2];
  const int*   batch = (const int*)d_in[3];
  const float* l0_ew = (const float*)d_in[4];
  const float* l0_eb = (const float*)d_in[5];
  const float* l0_w1 = (const float*)d_in[6];
  const float* l0_b1 = (const float*)d_in[7];
  const float* l0_w2 = (const float*)d_in[8];
  const float* l0_b2 = (const float*)d_in[9];
  const float* ew    = (const float*)d_in[10];
  const float* eb    = (const float*)d_in[11];
  const float* w1    = (const float*)d_in[12];
  const float* b1    = (const float*)d_in[13];
  const float* w2    = (const float*)d_in[14];
  const float* b2    = (const float*)d_in[15];
  const float* bng   = (const float*)d_in[16];
  const float* bnb   = (const float*)d_in[17];
  const float* hw1   = (const float*)d_in[18];
  const float* hb1   = (const float*)d_in[19];
  const float* hw2   = (const float*)d_in[20];
  const float* hb2   = (const float*)d_in[21];
  const int* esrc = ei;
  const int* edst = ei + NE;

  char* wsb = (char*)d_ws;
  size_t off = 0;
  auto A = [&](size_t bytes) -> void* {
    void* p = wsb + off;
    off = (off + bytes + 255) & ~(size_t)255;
    return p;
  };
  int*   csrc = (int*)A((size_t)NE * 4);
  int*   ceid = (int*)A((size_t)NE * 4);
  int*   offs = (int*)A((size_t)NN * 4);
  int*   deg  = (int*)A((size_t)NN * 4);
  int*   cur  = (int*)A((size_t)NN * 4);
  int2*  odeg = (int2*)A((size_t)NN * 8);
  int*   bsum = (int*)A(128 * 4);
  int*   gst  = (int*)A((NG + 1) * 4);
  float* xpad = (float*)A((size_t)NN * 64 * 4);
  float* hpre = (float*)A((size_t)NN * 64 * 4);
  float* h2   = (float*)A((size_t)NN * 64 * 4);
  float* bnsq = (float*)A(4 * 32 * 128 * 4);   // [layer][copy0..31][sum64|sq64]
  float* scs  = (float*)A(4 * 64 * 4);
  float* shs  = (float*)A(4 * 64 * 4);
  float* pooled = (float*)A((size_t)NG * 64 * 4);
  float* w2t  = (float*)A(4 * 4096 * 4);
  float* w1t  = (float*)A(4 * 4096 * 4);
  unsigned* ewh = (unsigned*)A(2048 * 4);   // f16-pair edge weights, 4 layers
  float* ebp  = (float*)A(256 * 4);         // padded edge biases, 4 layers
  unsigned* e16 = (unsigned*)A(((size_t)NE + 16) * 32);  // f16 eattr, CSR order, 8 dwords/edge

  hipMemsetAsync(deg, 0, (size_t)NN * 4, stream);
  hipMemsetAsync(bnsq, 0, 4 * 32 * 128 * 4, stream);
  hipMemsetAsync(pooled, 0, (size_t)NG * 64 * 4, stream);

  k_tr<<<64, 256, 0, stream>>>(l0_w2, w2, w2t);
  k_tr1<<<64, 256, 0, stream>>>(l0_w1, w1, w1t);
  k_wprep<<<8, 256, 0, stream>>>(l0_ew, l0_eb, ew, eb, ewh, ebp);
  k_xpad<<<(NN * 64 + 255) / 256, 256, 0, stream>>>(x_f, xpad);
  k_gstart<<<(NN + 255) / 256, 256, 0, stream>>>(batch, gst);

  k_deg<<<(NE + 255) / 256, 256, 0, stream>>>(edst, deg);
  k_scan1<<<98, 1024, 0, stream>>>(deg, offs, bsum);
  k_scan2<<<1, 128, 0, stream>>>(bsum, 98);
  k_scan3<<<(NN + 255) / 256, 256, 0, stream>>>(offs, bsum, deg, cur, odeg);
  k_fill<<<(NE + 255) / 256, 256, 0, stream>>>(esrc, edst, cur, csrc, ceid);
  k_cast<<<(NE + 255) / 256, 256, 0, stream>>>(ceid, (const float4*)eattr, (uint4*)e16);

  const int nodeBlocks = (NN * 64 + 255) / 256;
  const int rowBlocks = (NN + 63) / 64;

  // ---- layer 0 (padded to C=64; BN=false) ----
  k_edgeH<false><<<nodeBlocks, 256, 0, stream>>>(csrc, odeg, xpad, nullptr, nullptr,
                                                 e16, ewh, ebp, hpre);
  k_mlp<32><<<rowBlocks, 256, 0, stream>>>(hpre, w1t, l0_b1, w2t, l0_b2, h2, bnsq + 0);
  k_bnfin<<<1, 64, 0, stream>>>(bnsq, bng, bnb, 0, scs, shs);

  // ---- layers 1..3: gather from h2 with fused BN(prev)+relu ----
  for (int i = 0; i < 3; i++) {
    k_edgeH<true><<<nodeBlocks, 256, 0, stream>>>(csrc, odeg, h2,
                                                  scs + i * 64, shs + i * 64,
                                                  e16, ewh + (size_t)(i + 1) * 512, ebp + (i + 1) * 64, hpre);
    k_mlp<64><<<rowBlocks, 256, 0, stream>>>(hpre, w1t + (size_t)(i + 1) * 4096, b1 + (size_t)i * 64,
                                             w2t + (size_t)(i + 1) * 4096, b2 + (size_t)i * 64,
                                             h2, bnsq + (size_t)(i + 1) * 4096);
    k_bnfin<<<1, 64, 0, stream>>>(bnsq, bng, bnb, i + 1, scs, shs);
  }

  // ---- pool (applies BN layer 3) + head ----
  k_pool2<<<NG * 4, 256, 0, stream>>>(h2, scs + 3 * 64, shs + 3 * 64, gst, pooled);
  k_head<<<NG, 128, 0, stream>>>(pooled, gst, hw1, hb1, hw2, hb2, (float*)d_out);
}

// Round 4
// 1176.607 us; speedup vs baseline: 2.9627x; 1.1023x over previous
//
#include <hip/hip_runtime.h>
#include <hip/hip_fp16.h>

// Problem constants
#define NN 100000
#define NE 1600000
#define DIN 32
#define DE 16
#define HC 64
#define NL 4
#define MHC 128
#define OUTC 10
#define NG 128

typedef _Float16 half4_t __attribute__((ext_vector_type(4)));
typedef float f32x4 __attribute__((ext_vector_type(4)));

// ---- CSR build ----
__global__ __launch_bounds__(256) void k_deg(const int* __restrict__ dst, int* __restrict__ deg) {
  int e = blockIdx.x * 256 + threadIdx.x;
  if (e < NE) atomicAdd(&deg[dst[e]], 1);
}

__global__ __launch_bounds__(1024) void k_scan1(const int* __restrict__ deg, int* __restrict__ offs, int* __restrict__ bsum) {
  __shared__ int s[1024];
  int t = threadIdx.x;
  int i = blockIdx.x * 1024 + t;
  int v = (i < NN) ? deg[i] : 0;
  s[t] = v; __syncthreads();
  for (int d = 1; d < 1024; d <<= 1) {
    int x = 0;
    if (t >= d) x = s[t - d];
    __syncthreads();
    if (t >= d) s[t] += x;
    __syncthreads();
  }
  if (i < NN) offs[i] = s[t] - v;
  if (t == 1023) bsum[blockIdx.x] = s[t];
}

__global__ __launch_bounds__(128) void k_scan2(int* __restrict__ bsum, int nb) {
  __shared__ int s[128];
  int t = threadIdx.x;
  int v = (t < nb) ? bsum[t] : 0;
  s[t] = v; __syncthreads();
  for (int d = 1; d < 128; d <<= 1) {
    int x = 0;
    if (t >= d) x = s[t - d];
    __syncthreads();
    if (t >= d) s[t] += x;
    __syncthreads();
  }
  if (t < nb) bsum[t] = s[t] - v;
}

// also builds odeg = (start, deg) int2
__global__ __launch_bounds__(256) void k_scan3(int* __restrict__ offs, const int* __restrict__ bsum,
                                               const int* __restrict__ deg,
                                               int* __restrict__ cur, int2* __restrict__ odeg) {
  int i = blockIdx.x * 256 + threadIdx.x;
  if (i < NN) {
    int o = offs[i] + bsum[i >> 10];
    offs[i] = o;
    cur[i] = o;
    odeg[i] = make_int2(o, deg[i]);
  }
}

__global__ __launch_bounds__(256) void k_fill(const int* __restrict__ src, const int* __restrict__ dst,
                                              int* __restrict__ cur, int* __restrict__ csrc, int* __restrict__ ceid) {
  int e = blockIdx.x * 256 + threadIdx.x;
  if (e < NE) {
    int d = dst[e];
    int pos = atomicAdd(&cur[d], 1);
    csrc[pos] = src[e];
    ceid[pos] = e;
  }
}

// ---- gather-cast: eattr (f32, original order) -> e16 (f16-packed, CSR order) ----
__global__ __launch_bounds__(256) void k_cast(const int* __restrict__ ceid,
                                              const float4* __restrict__ eattr4,
                                              uint4* __restrict__ e16) {
  int p = blockIdx.x * 256 + threadIdx.x;
  if (p >= NE) return;
  int e = ceid[p];
  float4 a0 = eattr4[(size_t)e * 4 + 0];
  float4 a1 = eattr4[(size_t)e * 4 + 1];
  float4 a2 = eattr4[(size_t)e * 4 + 2];
  float4 a3 = eattr4[(size_t)e * 4 + 3];
  __half2 h0 = __floats2half2_rn(a0.x, a0.y), h1 = __floats2half2_rn(a0.z, a0.w);
  __half2 h2 = __floats2half2_rn(a1.x, a1.y), h3 = __floats2half2_rn(a1.z, a1.w);
  __half2 h4 = __floats2half2_rn(a2.x, a2.y), h5 = __floats2half2_rn(a2.z, a2.w);
  __half2 h6 = __floats2half2_rn(a3.x, a3.y), h7 = __floats2half2_rn(a3.z, a3.w);
  uint4 o0 = make_uint4(*(unsigned*)&h0, *(unsigned*)&h1, *(unsigned*)&h2, *(unsigned*)&h3);
  uint4 o1 = make_uint4(*(unsigned*)&h4, *(unsigned*)&h5, *(unsigned*)&h6, *(unsigned*)&h7);
  e16[(size_t)p * 2 + 0] = o0;
  e16[(size_t)p * 2 + 1] = o1;
}

// ---- edge weights -> MFMA B-fragment layout [4 layers][4 grp][64 lane][2 dw]
//      bf[g] for lane l = W[k = 4*(l>>4)+i][ch = 16g+(l&15)], i=0..3 (f16)
//      + padded biases [4][64] ----
__global__ __launch_bounds__(256) void k_wprep(const float* __restrict__ l0ew, const float* __restrict__ l0eb,
                                               const float* __restrict__ ew, const float* __restrict__ eb,
                                               unsigned* __restrict__ ewmf, float* __restrict__ ebp) {
  int i = blockIdx.x * 256 + threadIdx.x;
  if (i < 2048) {
    int j = i & 1;           // dword within lane fragment
    int l = (i >> 1) & 63;   // lane
    int g = (i >> 7) & 3;    // channel group
    int L = i >> 9;          // layer
    int ch = 16 * g + (l & 15);
    int k0 = 4 * (l >> 4) + 2 * j;
    float a, b;
    if (L == 0) {
      a = (ch < 32) ? l0ew[ch * 16 + k0] : 0.f;
      b = (ch < 32) ? l0ew[ch * 16 + k0 + 1] : 0.f;
    } else {
      a = ew[(size_t)(L - 1) * 1024 + ch * 16 + k0];
      b = ew[(size_t)(L - 1) * 1024 + ch * 16 + k0 + 1];
    }
    __half2 h = __floats2half2_rn(a, b);
    ewmf[i] = *(unsigned*)&h;
  }
  if (i < 256) {
    int L = i >> 6, c = i & 63;
    ebp[i] = (L == 0) ? ((c < 32) ? l0eb[c] : 0.f) : eb[(size_t)(L - 1) * 64 + c];
  }
}

// ---- graph boundaries (batch sorted) ----
__global__ __launch_bounds__(256) void k_gstart(const int* __restrict__ batch, int* __restrict__ gstart) {
  int i = blockIdx.x * 256 + threadIdx.x;
  if (i >= NN) return;
  int b = batch[i];
  int bp = (i == 0) ? -1 : batch[i - 1];
  for (int g = bp + 1; g <= b; g++) gstart[g] = i;
  if (i == NN - 1)
    for (int g = b + 1; g <= NG; g++) gstart[g] = NN;
}

// ---- w2 transpose: w2t[mat][c1][c2] = w2[mat][c2][c1] ----
__global__ __launch_bounds__(256) void k_tr(const float* __restrict__ l0w2, const float* __restrict__ w2,
                                            float* __restrict__ w2t) {
  int id = blockIdx.x * 256 + threadIdx.x;
  int mat = id >> 12;
  int j = id & 4095;
  int c1 = j >> 6, c2 = j & 63;
  const float* s = (mat == 0) ? l0w2 : (w2 + (size_t)(mat - 1) * 4096);
  w2t[mat * 4096 + j] = s[c2 * 64 + c1];
}

// ---- w1 transpose + pad: w1t[L][k][c1]; layer0 k>=32 zero-padded ----
__global__ __launch_bounds__(256) void k_tr1(const float* __restrict__ l0w1, const float* __restrict__ w1,
                                             float* __restrict__ w1t) {
  int id = blockIdx.x * 256 + threadIdx.x;
  if (id >= 4 * 4096) return;
  int L = id >> 12, j = id & 4095;
  int k = j >> 6, c = j & 63;
  float v;
  if (L == 0) v = (k < 32) ? l0w1[c * 32 + k] : 0.f;
  else v = w1[(size_t)(L - 1) * 4096 + c * 64 + k];
  w1t[id] = v;
}

__global__ __launch_bounds__(256) void k_xpad(const float* __restrict__ x, float* __restrict__ xpad) {
  int i = blockIdx.x * 256 + threadIdx.x;   // over NN*64
  if (i >= NN * 64) return;
  int cc = i & 63;
  xpad[i] = (cc < 32) ? x[(size_t)(i >> 6) * 32 + cc] : 0.f;
}

// ---- edge aggregation, v5: MFMA edge-linear.
//      R3 lesson: 8 readlane + 8 fdot2 per edge = VALU-bound (79% busy).
//      The edge transform is matmul-shaped: per 16-edge chunk, compute
//      [16 edges x 16 feat] x [16 feat x 64 ch] with 4x mfma_f32_16x16x16f16
//      (bias folded into the C operand). Wave per node as before.
//      A-frag: lane l = edge p+(l&15), k=4*(l>>4)+i (one coalesced dwordx2).
//      D-frag: lane l holds edges 4*(l>>4)+r, ch 16g+(l&15) -> per-lane
//      relu(x+el) accumulate, shfl_xor(16/32) reduce, lane=channel store. ----
template<bool BN>
__global__ __launch_bounds__(256) void k_edgeH(
    const int* __restrict__ csrc, const int2* __restrict__ odeg,
    const float* __restrict__ xsrc, const float* __restrict__ scp, const float* __restrict__ shp,
    const unsigned* __restrict__ e16,
    const unsigned* __restrict__ ewmf, const float* __restrict__ ebf,
    float* __restrict__ hpre)
{
  int gt = blockIdx.x * 256 + threadIdx.x;
  int node = gt >> 6;
  if (node >= NN) return;
  int c = threadIdx.x & 63;
  int m = c & 15;    // A row (edge-in-chunk) / ch-in-group
  int qv = c >> 4;   // lane quarter

  half4_t bf[4];
  #pragma unroll
  for (int g = 0; g < 4; g++) {
    uint2 wv = *(const uint2*)(ewmf + (size_t)(g * 64 + c) * 2);
    bf[g] = __builtin_bit_cast(half4_t, wv);
  }
  float bb[4], scv[4], shv[4];
  #pragma unroll
  for (int g = 0; g < 4; g++) {
    bb[g] = ebf[16 * g + m];
    if (BN) { scv[g] = scp[16 * g + m]; shv[g] = shp[16 * g + m]; }
  }
  int2 od = odeg[node];
  int start = od.x, n = od.y;
  float acc[4] = {0.f, 0.f, 0.f, 0.f};

  for (int base = 0; base < n; base += 16) {
    int cn = n - base;           // valid edges this chunk (may exceed 16)
    int p = start + base;
    // A fragment: coalesced 512B across the wave
    uint2 av = *(const uint2*)(e16 + (size_t)(p + m) * 8 + qv * 2);
    half4_t af = __builtin_bit_cast(half4_t, av);
    // edge linear: D[edge][ch] = A x B + bias
    f32x4 d0, d1, d2, d3;
    {
      f32x4 ci;
      ci[0] = bb[0]; ci[1] = bb[0]; ci[2] = bb[0]; ci[3] = bb[0];
      d0 = __builtin_amdgcn_mfma_f32_16x16x16f16(af, bf[0], ci, 0, 0, 0);
      ci[0] = bb[1]; ci[1] = bb[1]; ci[2] = bb[1]; ci[3] = bb[1];
      d1 = __builtin_amdgcn_mfma_f32_16x16x16f16(af, bf[1], ci, 0, 0, 0);
      ci[0] = bb[2]; ci[1] = bb[2]; ci[2] = bb[2]; ci[3] = bb[2];
      d2 = __builtin_amdgcn_mfma_f32_16x16x16f16(af, bf[2], ci, 0, 0, 0);
      ci[0] = bb[3]; ci[1] = bb[3]; ci[2] = bb[3]; ci[3] = bb[3];
      d3 = __builtin_amdgcn_mfma_f32_16x16x16f16(af, bf[3], ci, 0, 0, 0);
    }
    // src broadcast: lane holds csrc[p+m]; my 4 edges are 4*qv+r
    int sidx = csrc[p + m];
    int s[4];
    #pragma unroll
    for (int r = 0; r < 4; r++) s[r] = __shfl(sidx, 4 * qv + r);
    #pragma unroll
    for (int r = 0; r < 4; r++) {
      bool valid = (4 * qv + r) < cn;
      const float* xp = xsrc + (size_t)s[r] * 64 + m;
      #pragma unroll
      for (int g = 0; g < 4; g++) {
        float xs = valid ? xp[16 * g] : 0.f;
        if (BN) xs = fmaxf(fmaf(xs, scv[g], shv[g]), 0.f);
        float el = (r == 0) ? ((g == 0) ? d0[0] : (g == 1) ? d1[0] : (g == 2) ? d2[0] : d3[0])
                 : (r == 1) ? ((g == 0) ? d0[1] : (g == 1) ? d1[1] : (g == 2) ? d2[1] : d3[1])
                 : (r == 2) ? ((g == 0) ? d0[2] : (g == 1) ? d1[2] : (g == 2) ? d2[2] : d3[2])
                 :            ((g == 0) ? d0[3] : (g == 1) ? d1[3] : (g == 2) ? d2[3] : d3[3]);
        float v = fmaxf(xs + el, 0.f);
        acc[g] += valid ? v : 0.f;
      }
    }
  }
  // reduce across lane quarters (edge split)
  #pragma unroll
  for (int g = 0; g < 4; g++) {
    acc[g] += __shfl_xor(acc[g], 16);
    acc[g] += __shfl_xor(acc[g], 32);
  }
  float xself = xsrc[(size_t)node * 64 + c];
  if (BN) xself = fmaxf(fmaf(xself, scp[c], shp[c]), 0.f);
  float sum = (qv == 0) ? acc[0] : (qv == 1) ? acc[1] : (qv == 2) ? acc[2] : acc[3];
  hpre[(size_t)node * 64 + c] = xself + sum;
}

// ---- fused node MLP + BN-stats epilogue, v4: weights staged in LDS. ----
template<int CIN>
__global__ __launch_bounds__(256) void k_mlp(
    const float* __restrict__ hpre,
    const float* __restrict__ w1tf, const float* __restrict__ b1f,
    const float* __restrict__ w2tf, const float* __restrict__ b2v,
    float* __restrict__ h2, float* __restrict__ bnsq)
{
  __shared__ float wl[64 * 64];   // weight tile (16KB), w1 then w2
  __shared__ float hl[64 * 65];   // act tile, pad 65 -> 2-way bank = free
  int tid = threadIdx.x;
  int wid = __builtin_amdgcn_readfirstlane(tid >> 6);
  int lane = tid & 63;
  int rbase = blockIdx.x * 64;
  // stage w1 -> LDS (coalesced: wave reads 1KB contiguous)
  {
    const float4* s = (const float4*)w1tf;
    float4* d = (float4*)wl;
    #pragma unroll
    for (int q = 0; q < 4; q++) d[tid + 256 * q] = s[tid + 256 * q];
  }
  // stage act tile: thread t -> row t>>2, k-offset (t&3)*16
  {
    int r = tid >> 2, ko = (tid & 3) * 16;
    int rg = rbase + r;
    float4 v0, v1, v2, v3;
    if (rg < NN) {
      const float4* src = (const float4*)(hpre + (size_t)rg * 64 + ko);
      v0 = src[0]; v1 = src[1]; v2 = src[2]; v3 = src[3];
    } else {
      v0 = v1 = v2 = v3 = make_float4(0.f, 0.f, 0.f, 0.f);
    }
    float* d = hl + r * 65 + ko;
    *(float4*)(d + 0) = v0; *(float4*)(d + 4) = v1;
    *(float4*)(d + 8) = v2; *(float4*)(d + 12) = v3;
  }
  // issue w2 global loads early (written to LDS after stage-A sync)
  float4 w2r[4];
  {
    const float4* s = (const float4*)w2tf;
    #pragma unroll
    for (int q = 0; q < 4; q++) w2r[q] = s[tid + 256 * q];
  }
  __syncthreads();
  int w16 = wid * 16;
  const float* hrow = hl + lane * 65;
  // preload this row's activations into registers
  float hreg[CIN];
  #pragma unroll
  for (int k0 = 0; k0 < CIN; k0 += 4) {
    float4 v = *(const float4*)(hrow + k0);
    hreg[k0] = v.x; hreg[k0+1] = v.y; hreg[k0+2] = v.z; hreg[k0+3] = v.w;
  }
  // stage A: mids[w16+j] = relu(b1 + sum_k w1t[k][w16+j] * h[k])
  float acc[16];
  #pragma unroll
  for (int j = 0; j < 16; j++) acc[j] = b1f[w16 + j];
  #pragma unroll
  for (int k = 0; k < CIN; k++) {
    const float* wr = wl + k * 64 + w16;   // wave-uniform LDS -> broadcast
    float hv = hreg[k];
    #pragma unroll
    for (int j = 0; j < 16; j++) acc[j] = fmaf(wr[j], hv, acc[j]);
  }
  #pragma unroll
  for (int j = 0; j < 16; j++) acc[j] = fmaxf(acc[j], 0.f);
  __syncthreads();   // all reads of wl (w1) and hl (h) done
  // write w2 into weight tile; write mids into act tile
  {
    float4* d = (float4*)wl;
    #pragma unroll
    for (int q = 0; q < 4; q++) d[tid + 256 * q] = w2r[q];
  }
  {
    float* d = hl + lane * 65 + w16;
    *(float4*)(d + 0)  = make_float4(acc[0], acc[1], acc[2], acc[3]);
    *(float4*)(d + 4)  = make_float4(acc[4], acc[5], acc[6], acc[7]);
    *(float4*)(d + 8)  = make_float4(acc[8], acc[9], acc[10], acc[11]);
    *(float4*)(d + 12) = make_float4(acc[12], acc[13], acc[14], acc[15]);
  }
  __syncthreads();
  // preload mids
  float mreg[64];
  #pragma unroll
  for (int k0 = 0; k0 < 64; k0 += 4) {
    float4 v = *(const float4*)(hrow + k0);
    mreg[k0] = v.x; mreg[k0+1] = v.y; mreg[k0+2] = v.z; mreg[k0+3] = v.w;
  }
  // stage B: out[w16+j] = relu(b2 + sum_c1 w2t[c1][w16+j] * mid[c1])
  float out[16];
  #pragma unroll
  for (int j = 0; j < 16; j++) out[j] = b2v[w16 + j];
  #pragma unroll
  for (int k = 0; k < 64; k++) {
    const float* wr = wl + k * 64 + w16;   // broadcast
    float mv = mreg[k];
    #pragma unroll
    for (int j = 0; j < 16; j++) out[j] = fmaf(wr[j], mv, out[j]);
  }
  bool act = (rbase + lane) < NN;
  #pragma unroll
  for (int j = 0; j < 16; j++) out[j] = act ? fmaxf(out[j], 0.f) : 0.f;
  if (act) {
    float4* dst = (float4*)(h2 + (size_t)(rbase + lane) * 64 + w16);
    dst[0] = make_float4(out[0], out[1], out[2], out[3]);
    dst[1] = make_float4(out[4], out[5], out[6], out[7]);
    dst[2] = make_float4(out[8], out[9], out[10], out[11]);
    dst[3] = make_float4(out[12], out[13], out[14], out[15]);
  }
  // BN partial stats: wave reduce over rows (lanes), lane0 atomics to 1-of-32 copies
  int cp = (blockIdx.x & 31) * 128;
  #pragma unroll
  for (int j = 0; j < 16; j++) {
    float s = out[j], q = s * s;
    #pragma unroll
    for (int mm = 1; mm < 64; mm <<= 1) { s += __shfl_xor(s, mm); q += __shfl_xor(q, mm); }
    if (lane == 0) {
      atomicAdd(&bnsq[cp + w16 + j], s);
      atomicAdd(&bnsq[cp + 64 + w16 + j], q);
    }
  }
}

__global__ __launch_bounds__(64) void k_bnfin(const float* __restrict__ bnsq,
                                              const float* __restrict__ gamma, const float* __restrict__ beta,
                                              int layer, float* __restrict__ scs, float* __restrict__ shs) {
  int c = threadIdx.x;
  if (c >= 64) return;
  const float* sl = bnsq + (size_t)layer * 4096;
  float s = 0.f, q = 0.f;
  for (int cp = 0; cp < 32; cp++) { s += sl[cp * 128 + c]; q += sl[cp * 128 + 64 + c]; }
  float mu = s * (1.0f / NN);
  float var = q * (1.0f / NN) - mu * mu;
  float r = rsqrtf(var + 1e-5f);
  float g = gamma[layer * 64 + c] * r;
  scs[layer * 64 + c] = g;
  shs[layer * 64 + c] = beta[layer * 64 + c] - mu * g;
}

// ---- pool: BN+relu on the fly; batch sorted -> contiguous ranges ----
__global__ __launch_bounds__(256) void k_pool2(const float* __restrict__ h2, const float* __restrict__ sc,
                                               const float* __restrict__ sh, const int* __restrict__ gstart,
                                               float* __restrict__ pooled) {
  int g = blockIdx.x >> 2, sub = blockIdx.x & 3;
  int s = gstart[g], e = gstart[g + 1];
  int c = threadIdx.x & 63, rg = threadIdx.x >> 6;
  float scv = sc[c], shv = sh[c];
  float acc = 0.f;
  for (int r = s + sub * 4 + rg; r < e; r += 16)
    acc += fmaxf(fmaf(h2[(size_t)r * 64 + c], scv, shv), 0.f);
  __shared__ float ls[256];
  ls[threadIdx.x] = acc;
  __syncthreads();
  if (rg == 0) {
    float v = ls[c] + ls[64 + c] + ls[128 + c] + ls[192 + c];
    atomicAdd(&pooled[g * 64 + c], v);
  }
}

__global__ __launch_bounds__(128) void k_head(const float* __restrict__ pooled, const int* __restrict__ gstart,
                                              const float* __restrict__ hw1, const float* __restrict__ hb1,
                                              const float* __restrict__ hw2, const float* __restrict__ hb2,
                                              float* __restrict__ out) {
  __shared__ float p[64];
  __shared__ float z[128];
  int g = blockIdx.x, t = threadIdx.x;
  if (t < 64) {
    int cn = gstart[g + 1] - gstart[g];
    float inv = 1.0f / (float)(cn > 0 ? cn : 1);
    p[t] = pooled[g * 64 + t] * inv;
  }
  __syncthreads();
  float a = hb1[t];
  #pragma unroll
  for (int k = 0; k < 64; k++) a = fmaf(hw1[t * 64 + k], p[k], a);
  z[t] = fmaxf(a, 0.f);
  __syncthreads();
  if (t < OUTC) {
    float b = hb2[t];
    #pragma unroll
    for (int k = 0; k < 128; k++) b = fmaf(hw2[t * 128 + k], z[k], b);
    out[g * OUTC + t] = b;
  }
}

extern "C" void kernel_launch(void* const* d_in, const int* in_sizes, int n_in,
                              void* d_out, int out_size, void* d_ws, size_t ws_size,
                              hipStream_t stream) {
  const float* x_f   = (const float*)d_in[0];
  const int*   ei    = (const int*)d_in[1];
  const float* eattr = (const float*)d_in[2];
  const int*   batch = (const int*)d_in[3];
  const float* l0_ew = (const float*)d_in[4];
  const float* l0_eb = (const float*)d_in[5];
  const float* l0_w1 = (const float*)d_in[6];
  const float* l0_b1 = (const float*)d_in[7];
  const float* l0_w2 = (const float*)d_in[8];
  const float* l0_b2 = (const float*)d_in[9];
  const float* ew    = (const float*)d_in[10];
  const float* eb    = (const float*)d_in[11];
  const float* w1    = (const float*)d_in[12];
  const float* b1    = (const float*)d_in[13];
  const float* w2    = (const float*)d_in[14];
  const float* b2    = (const float*)d_in[15];
  const float* bng   = (const float*)d_in[16];
  const float* bnb   = (const float*)d_in[17];
  const float* hw1   = (const float*)d_in[18];
  const float* hb1   = (const float*)d_in[19];
  const float* hw2   = (const float*)d_in[20];
  const float* hb2   = (const float*)d_in[21];
  const int* esrc = ei;
  const int* edst = ei + NE;

  char* wsb = (char*)d_ws;
  size_t off = 0;
  auto A = [&](size_t bytes) -> void* {
    void* p = wsb + off;
    off = (off + bytes + 255) & ~(size_t)255;
    return p;
  };
  int*   csrc = (int*)A((size_t)(NE + 16) * 4);
  int*   ceid = (int*)A((size_t)NE * 4);
  int*   offs = (int*)A((size_t)NN * 4);
  int*   deg  = (int*)A((size_t)NN * 4);
  int*   cur  = (int*)A((size_t)NN * 4);
  int2*  odeg = (int2*)A((size_t)NN * 8);
  int*   bsum = (int*)A(128 * 4);
  int*   gst  = (int*)A((NG + 1) * 4);
  float* xpad = (float*)A((size_t)NN * 64 * 4);
  float* hpre = (float*)A((size_t)NN * 64 * 4);
  float* h2   = (float*)A((size_t)NN * 64 * 4);
  float* bnsq = (float*)A(4 * 32 * 128 * 4);   // [layer][copy0..31][sum64|sq64]
  float* scs  = (float*)A(4 * 64 * 4);
  float* shs  = (float*)A(4 * 64 * 4);
  float* pooled = (float*)A((size_t)NG * 64 * 4);
  float* w2t  = (float*)A(4 * 4096 * 4);
  float* w1t  = (float*)A(4 * 4096 * 4);
  unsigned* ewmf = (unsigned*)A(2048 * 4);  // MFMA-layout f16 edge weights, 4 layers
  float* ebp  = (float*)A(256 * 4);         // padded edge biases, 4 layers
  unsigned* e16 = (unsigned*)A(((size_t)NE + 16) * 32);  // f16 eattr, CSR order, 8 dwords/edge

  hipMemsetAsync(deg, 0, (size_t)NN * 4, stream);
  hipMemsetAsync(bnsq, 0, 4 * 32 * 128 * 4, stream);
  hipMemsetAsync(pooled, 0, (size_t)NG * 64 * 4, stream);
  hipMemsetAsync(csrc + NE, 0, 16 * 4, stream);            // pad: safe src idx for tail chunks
  hipMemsetAsync((char*)e16 + (size_t)NE * 32, 0, 16 * 32, stream);  // pad: clean A-frag tail

  k_tr<<<64, 256, 0, stream>>>(l0_w2, w2, w2t);
  k_tr1<<<64, 256, 0, stream>>>(l0_w1, w1, w1t);
  k_wprep<<<8, 256, 0, stream>>>(l0_ew, l0_eb, ew, eb, ewmf, ebp);
  k_xpad<<<(NN * 64 + 255) / 256, 256, 0, stream>>>(x_f, xpad);
  k_gstart<<<(NN + 255) / 256, 256, 0, stream>>>(batch, gst);

  k_deg<<<(NE + 255) / 256, 256, 0, stream>>>(edst, deg);
  k_scan1<<<98, 1024, 0, stream>>>(deg, offs, bsum);
  k_scan2<<<1, 128, 0, stream>>>(bsum, 98);
  k_scan3<<<(NN + 255) / 256, 256, 0, stream>>>(offs, bsum, deg, cur, odeg);
  k_fill<<<(NE + 255) / 256, 256, 0, stream>>>(esrc, edst, cur, csrc, ceid);
  k_cast<<<(NE + 255) / 256, 256, 0, stream>>>(ceid, (const float4*)eattr, (uint4*)e16);

  const int nodeBlocks = (NN * 64 + 255) / 256;
  const int rowBlocks = (NN + 63) / 64;

  // ---- layer 0 (padded to C=64; BN=false) ----
  k_edgeH<false><<<nodeBlocks, 256, 0, stream>>>(csrc, odeg, xpad, nullptr, nullptr,
                                                 e16, ewmf, ebp, hpre);
  k_mlp<32><<<rowBlocks, 256, 0, stream>>>(hpre, w1t, l0_b1, w2t, l0_b2, h2, bnsq + 0);
  k_bnfin<<<1, 64, 0, stream>>>(bnsq, bng, bnb, 0, scs, shs);

  // ---- layers 1..3: gather from h2 with fused BN(prev)+relu ----
  for (int i = 0; i < 3; i++) {
    k_edgeH<true><<<nodeBlocks, 256, 0, stream>>>(csrc, odeg, h2,
                                                  scs + i * 64, shs + i * 64,
                                                  e16, ewmf + (size_t)(i + 1) * 512, ebp + (i + 1) * 64, hpre);
    k_mlp<64><<<rowBlocks, 256, 0, stream>>>(hpre, w1t + (size_t)(i + 1) * 4096, b1 + (size_t)i * 64,
                                             w2t + (size_t)(i + 1) * 4096, b2 + (size_t)i * 64,
                                             h2, bnsq + (size_t)(i + 1) * 4096);
    k_bnfin<<<1, 64, 0, stream>>>(bnsq, bng, bnb, i + 1, scs, shs);
  }

  // ---- pool (applies BN layer 3) + head ----
  k_pool2<<<NG * 4, 256, 0, stream>>>(h2, scs + 3 * 64, shs + 3 * 64, gst, pooled);
  k_head<<<NG, 128, 0, stream>>>(pooled, gst, hw1, hb1, hw2, hb2, (float*)d_out);
}

// Round 5
// 1109.291 us; speedup vs baseline: 3.1425x; 1.0607x over previous
//
#include <hip/hip_runtime.h>
#include <hip/hip_fp16.h>

// Problem constants
#define NN 100000
#define NE 1600000
#define DIN 32
#define DE 16
#define HC 64
#define NL 4
#define MHC 128
#define OUTC 10
#define NG 128

typedef _Float16 half4_t __attribute__((ext_vector_type(4)));
typedef float f32x4 __attribute__((ext_vector_type(4)));

// ---- CSR build ----
__global__ __launch_bounds__(256) void k_deg(const int* __restrict__ dst, int* __restrict__ deg) {
  int e = blockIdx.x * 256 + threadIdx.x;
  if (e < NE) atomicAdd(&deg[dst[e]], 1);
}

__global__ __launch_bounds__(1024) void k_scan1(const int* __restrict__ deg, int* __restrict__ offs, int* __restrict__ bsum) {
  __shared__ int s[1024];
  int t = threadIdx.x;
  int i = blockIdx.x * 1024 + t;
  int v = (i < NN) ? deg[i] : 0;
  s[t] = v; __syncthreads();
  for (int d = 1; d < 1024; d <<= 1) {
    int x = 0;
    if (t >= d) x = s[t - d];
    __syncthreads();
    if (t >= d) s[t] += x;
    __syncthreads();
  }
  if (i < NN) offs[i] = s[t] - v;
  if (t == 1023) bsum[blockIdx.x] = s[t];
}

__global__ __launch_bounds__(128) void k_scan2(int* __restrict__ bsum, int nb) {
  __shared__ int s[128];
  int t = threadIdx.x;
  int v = (t < nb) ? bsum[t] : 0;
  s[t] = v; __syncthreads();
  for (int d = 1; d < 128; d <<= 1) {
    int x = 0;
    if (t >= d) x = s[t - d];
    __syncthreads();
    if (t >= d) s[t] += x;
    __syncthreads();
  }
  if (t < nb) bsum[t] = s[t] - v;
}

// also builds odeg = (start, deg) int2
__global__ __launch_bounds__(256) void k_scan3(int* __restrict__ offs, const int* __restrict__ bsum,
                                               const int* __restrict__ deg,
                                               int* __restrict__ cur, int2* __restrict__ odeg) {
  int i = blockIdx.x * 256 + threadIdx.x;
  if (i < NN) {
    int o = offs[i] + bsum[i >> 10];
    offs[i] = o;
    cur[i] = o;
    odeg[i] = make_int2(o, deg[i]);
  }
}

// ---- fused fill + cast: one pass over edges (coalesced reads of src/dst/eattr),
//      scatter-write csrc (4B) + e16 (32B, single 64B line) at CSR position.
//      R4 lesson: k_fill was write-line-bound (154MB lines for 13MB data);
//      fusing kills the ceid array and k_cast's random eattr gather entirely. ----
__global__ __launch_bounds__(256) void k_fillcast(const int* __restrict__ src, const int* __restrict__ dst,
                                                  int* __restrict__ cur,
                                                  const float4* __restrict__ eattr4,
                                                  int* __restrict__ csrc, uint4* __restrict__ e16) {
  int e = blockIdx.x * 256 + threadIdx.x;
  if (e >= NE) return;
  int d = dst[e];
  // coalesced streaming reads at original edge index
  float4 a0 = eattr4[(size_t)e * 4 + 0];
  float4 a1 = eattr4[(size_t)e * 4 + 1];
  float4 a2 = eattr4[(size_t)e * 4 + 2];
  float4 a3 = eattr4[(size_t)e * 4 + 3];
  int s = src[e];
  int pos = atomicAdd(&cur[d], 1);
  __half2 h0 = __floats2half2_rn(a0.x, a0.y), h1 = __floats2half2_rn(a0.z, a0.w);
  __half2 h2 = __floats2half2_rn(a1.x, a1.y), h3 = __floats2half2_rn(a1.z, a1.w);
  __half2 h4 = __floats2half2_rn(a2.x, a2.y), h5 = __floats2half2_rn(a2.z, a2.w);
  __half2 h6 = __floats2half2_rn(a3.x, a3.y), h7 = __floats2half2_rn(a3.z, a3.w);
  uint4 o0 = make_uint4(*(unsigned*)&h0, *(unsigned*)&h1, *(unsigned*)&h2, *(unsigned*)&h3);
  uint4 o1 = make_uint4(*(unsigned*)&h4, *(unsigned*)&h5, *(unsigned*)&h6, *(unsigned*)&h7);
  csrc[pos] = s;
  e16[(size_t)pos * 2 + 0] = o0;   // pos*32 .. pos*32+31: one 64B line
  e16[(size_t)pos * 2 + 1] = o1;
}

// ---- edge weights -> MFMA B-fragment layout [4 layers][4 grp][64 lane][2 dw]
//      bf[g] for lane l = W[k = 4*(l>>4)+i][ch = 16g+(l&15)], i=0..3 (f16)
//      + padded biases [4][64] ----
__global__ __launch_bounds__(256) void k_wprep(const float* __restrict__ l0ew, const float* __restrict__ l0eb,
                                               const float* __restrict__ ew, const float* __restrict__ eb,
                                               unsigned* __restrict__ ewmf, float* __restrict__ ebp) {
  int i = blockIdx.x * 256 + threadIdx.x;
  if (i < 2048) {
    int j = i & 1;           // dword within lane fragment
    int l = (i >> 1) & 63;   // lane
    int g = (i >> 7) & 3;    // channel group
    int L = i >> 9;          // layer
    int ch = 16 * g + (l & 15);
    int k0 = 4 * (l >> 4) + 2 * j;
    float a, b;
    if (L == 0) {
      a = (ch < 32) ? l0ew[ch * 16 + k0] : 0.f;
      b = (ch < 32) ? l0ew[ch * 16 + k0 + 1] : 0.f;
    } else {
      a = ew[(size_t)(L - 1) * 1024 + ch * 16 + k0];
      b = ew[(size_t)(L - 1) * 1024 + ch * 16 + k0 + 1];
    }
    __half2 h = __floats2half2_rn(a, b);
    ewmf[i] = *(unsigned*)&h;
  }
  if (i < 256) {
    int L = i >> 6, c = i & 63;
    ebp[i] = (L == 0) ? ((c < 32) ? l0eb[c] : 0.f) : eb[(size_t)(L - 1) * 64 + c];
  }
}

// ---- graph boundaries (batch sorted) ----
__global__ __launch_bounds__(256) void k_gstart(const int* __restrict__ batch, int* __restrict__ gstart) {
  int i = blockIdx.x * 256 + threadIdx.x;
  if (i >= NN) return;
  int b = batch[i];
  int bp = (i == 0) ? -1 : batch[i - 1];
  for (int g = bp + 1; g <= b; g++) gstart[g] = i;
  if (i == NN - 1)
    for (int g = b + 1; g <= NG; g++) gstart[g] = NN;
}

// ---- w2 transpose: w2t[mat][c1][c2] = w2[mat][c2][c1] ----
__global__ __launch_bounds__(256) void k_tr(const float* __restrict__ l0w2, const float* __restrict__ w2,
                                            float* __restrict__ w2t) {
  int id = blockIdx.x * 256 + threadIdx.x;
  int mat = id >> 12;
  int j = id & 4095;
  int c1 = j >> 6, c2 = j & 63;
  const float* s = (mat == 0) ? l0w2 : (w2 + (size_t)(mat - 1) * 4096);
  w2t[mat * 4096 + j] = s[c2 * 64 + c1];
}

// ---- w1 transpose + pad: w1t[L][k][c1]; layer0 k>=32 zero-padded ----
__global__ __launch_bounds__(256) void k_tr1(const float* __restrict__ l0w1, const float* __restrict__ w1,
                                             float* __restrict__ w1t) {
  int id = blockIdx.x * 256 + threadIdx.x;
  if (id >= 4 * 4096) return;
  int L = id >> 12, j = id & 4095;
  int k = j >> 6, c = j & 63;
  float v;
  if (L == 0) v = (k < 32) ? l0w1[c * 32 + k] : 0.f;
  else v = w1[(size_t)(L - 1) * 4096 + c * 64 + k];
  w1t[id] = v;
}

__global__ __launch_bounds__(256) void k_xpad(const float* __restrict__ x, float* __restrict__ xpad) {
  int i = blockIdx.x * 256 + threadIdx.x;   // over NN*64
  if (i >= NN * 64) return;
  int cc = i & 63;
  xpad[i] = (cc < 32) ? x[(size_t)(i >> 6) * 32 + cc] : 0.f;
}

// ---- edge aggregation, v5: MFMA edge-linear.
//      Per 16-edge chunk: [16 edges x 16 feat] x [16 feat x 64 ch] via
//      4x mfma_f32_16x16x16f16 (bias folded into C). Wave per node.
//      A-frag: lane l = edge p+(l&15), k=4*(l>>4)+i (coalesced dwordx2).
//      D-frag: lane l holds edges 4*(l>>4)+r, ch 16g+(l&15) -> per-lane
//      relu(x+el) accumulate, shfl_xor(16/32) reduce, lane=channel store. ----
template<bool BN>
__global__ __launch_bounds__(256) void k_edgeH(
    const int* __restrict__ csrc, const int2* __restrict__ odeg,
    const float* __restrict__ xsrc, const float* __restrict__ scp, const float* __restrict__ shp,
    const unsigned* __restrict__ e16,
    const unsigned* __restrict__ ewmf, const float* __restrict__ ebf,
    float* __restrict__ hpre)
{
  int gt = blockIdx.x * 256 + threadIdx.x;
  int node = gt >> 6;
  if (node >= NN) return;
  int c = threadIdx.x & 63;
  int m = c & 15;    // A row (edge-in-chunk) / ch-in-group
  int qv = c >> 4;   // lane quarter

  half4_t bf[4];
  #pragma unroll
  for (int g = 0; g < 4; g++) {
    uint2 wv = *(const uint2*)(ewmf + (size_t)(g * 64 + c) * 2);
    bf[g] = __builtin_bit_cast(half4_t, wv);
  }
  float bb[4], scv[4], shv[4];
  #pragma unroll
  for (int g = 0; g < 4; g++) {
    bb[g] = ebf[16 * g + m];
    if (BN) { scv[g] = scp[16 * g + m]; shv[g] = shp[16 * g + m]; }
  }
  int2 od = odeg[node];
  int start = od.x, n = od.y;
  float acc[4] = {0.f, 0.f, 0.f, 0.f};

  for (int base = 0; base < n; base += 16) {
    int cn = n - base;           // valid edges this chunk (may exceed 16)
    int p = start + base;
    // A fragment: coalesced 512B across the wave
    uint2 av = *(const uint2*)(e16 + (size_t)(p + m) * 8 + qv * 2);
    half4_t af = __builtin_bit_cast(half4_t, av);
    // edge linear: D[edge][ch] = A x B + bias
    f32x4 d0, d1, d2, d3;
    {
      f32x4 ci;
      ci[0] = bb[0]; ci[1] = bb[0]; ci[2] = bb[0]; ci[3] = bb[0];
      d0 = __builtin_amdgcn_mfma_f32_16x16x16f16(af, bf[0], ci, 0, 0, 0);
      ci[0] = bb[1]; ci[1] = bb[1]; ci[2] = bb[1]; ci[3] = bb[1];
      d1 = __builtin_amdgcn_mfma_f32_16x16x16f16(af, bf[1], ci, 0, 0, 0);
      ci[0] = bb[2]; ci[1] = bb[2]; ci[2] = bb[2]; ci[3] = bb[2];
      d2 = __builtin_amdgcn_mfma_f32_16x16x16f16(af, bf[2], ci, 0, 0, 0);
      ci[0] = bb[3]; ci[1] = bb[3]; ci[2] = bb[3]; ci[3] = bb[3];
      d3 = __builtin_amdgcn_mfma_f32_16x16x16f16(af, bf[3], ci, 0, 0, 0);
    }
    // src broadcast: lane holds csrc[p+m]; my 4 edges are 4*qv+r
    int sidx = csrc[p + m];
    int s[4];
    #pragma unroll
    for (int r = 0; r < 4; r++) s[r] = __shfl(sidx, 4 * qv + r);
    #pragma unroll
    for (int r = 0; r < 4; r++) {
      bool valid = (4 * qv + r) < cn;
      const float* xp = xsrc + (size_t)s[r] * 64 + m;
      #pragma unroll
      for (int g = 0; g < 4; g++) {
        float xs = valid ? xp[16 * g] : 0.f;
        if (BN) xs = fmaxf(fmaf(xs, scv[g], shv[g]), 0.f);
        float el = (r == 0) ? ((g == 0) ? d0[0] : (g == 1) ? d1[0] : (g == 2) ? d2[0] : d3[0])
                 : (r == 1) ? ((g == 0) ? d0[1] : (g == 1) ? d1[1] : (g == 2) ? d2[1] : d3[1])
                 : (r == 2) ? ((g == 0) ? d0[2] : (g == 1) ? d1[2] : (g == 2) ? d2[2] : d3[2])
                 :            ((g == 0) ? d0[3] : (g == 1) ? d1[3] : (g == 2) ? d2[3] : d3[3]);
        float v = fmaxf(xs + el, 0.f);
        acc[g] += valid ? v : 0.f;
      }
    }
  }
  // reduce across lane quarters (edge split)
  #pragma unroll
  for (int g = 0; g < 4; g++) {
    acc[g] += __shfl_xor(acc[g], 16);
    acc[g] += __shfl_xor(acc[g], 32);
  }
  float xself = xsrc[(size_t)node * 64 + c];
  if (BN) xself = fmaxf(fmaf(xself, scp[c], shp[c]), 0.f);
  float sum = (qv == 0) ? acc[0] : (qv == 1) ? acc[1] : (qv == 2) ? acc[2] : acc[3];
  hpre[(size_t)node * 64 + c] = xself + sum;
}

// ---- fused node MLP + BN-stats epilogue, v4: weights staged in LDS. ----
template<int CIN>
__global__ __launch_bounds__(256) void k_mlp(
    const float* __restrict__ hpre,
    const float* __restrict__ w1tf, const float* __restrict__ b1f,
    const float* __restrict__ w2tf, const float* __restrict__ b2v,
    float* __restrict__ h2, float* __restrict__ bnsq)
{
  __shared__ float wl[64 * 64];   // weight tile (16KB), w1 then w2
  __shared__ float hl[64 * 65];   // act tile, pad 65 -> 2-way bank = free
  int tid = threadIdx.x;
  int wid = __builtin_amdgcn_readfirstlane(tid >> 6);
  int lane = tid & 63;
  int rbase = blockIdx.x * 64;
  // stage w1 -> LDS (coalesced: wave reads 1KB contiguous)
  {
    const float4* s = (const float4*)w1tf;
    float4* d = (float4*)wl;
    #pragma unroll
    for (int q = 0; q < 4; q++) d[tid + 256 * q] = s[tid + 256 * q];
  }
  // stage act tile: thread t -> row t>>2, k-offset (t&3)*16
  {
    int r = tid >> 2, ko = (tid & 3) * 16;
    int rg = rbase + r;
    float4 v0, v1, v2, v3;
    if (rg < NN) {
      const float4* src = (const float4*)(hpre + (size_t)rg * 64 + ko);
      v0 = src[0]; v1 = src[1]; v2 = src[2]; v3 = src[3];
    } else {
      v0 = v1 = v2 = v3 = make_float4(0.f, 0.f, 0.f, 0.f);
    }
    float* d = hl + r * 65 + ko;
    *(float4*)(d + 0) = v0; *(float4*)(d + 4) = v1;
    *(float4*)(d + 8) = v2; *(float4*)(d + 12) = v3;
  }
  // issue w2 global loads early (written to LDS after stage-A sync)
  float4 w2r[4];
  {
    const float4* s = (const float4*)w2tf;
    #pragma unroll
    for (int q = 0; q < 4; q++) w2r[q] = s[tid + 256 * q];
  }
  __syncthreads();
  int w16 = wid * 16;
  const float* hrow = hl + lane * 65;
  // preload this row's activations into registers
  float hreg[CIN];
  #pragma unroll
  for (int k0 = 0; k0 < CIN; k0 += 4) {
    float4 v = *(const float4*)(hrow + k0);
    hreg[k0] = v.x; hreg[k0+1] = v.y; hreg[k0+2] = v.z; hreg[k0+3] = v.w;
  }
  // stage A: mids[w16+j] = relu(b1 + sum_k w1t[k][w16+j] * h[k])
  float acc[16];
  #pragma unroll
  for (int j = 0; j < 16; j++) acc[j] = b1f[w16 + j];
  #pragma unroll
  for (int k = 0; k < CIN; k++) {
    const float* wr = wl + k * 64 + w16;   // wave-uniform LDS -> broadcast
    float hv = hreg[k];
    #pragma unroll
    for (int j = 0; j < 16; j++) acc[j] = fmaf(wr[j], hv, acc[j]);
  }
  #pragma unroll
  for (int j = 0; j < 16; j++) acc[j] = fmaxf(acc[j], 0.f);
  __syncthreads();   // all reads of wl (w1) and hl (h) done
  // write w2 into weight tile; write mids into act tile
  {
    float4* d = (float4*)wl;
    #pragma unroll
    for (int q = 0; q < 4; q++) d[tid + 256 * q] = w2r[q];
  }
  {
    float* d = hl + lane * 65 + w16;
    *(float4*)(d + 0)  = make_float4(acc[0], acc[1], acc[2], acc[3]);
    *(float4*)(d + 4)  = make_float4(acc[4], acc[5], acc[6], acc[7]);
    *(float4*)(d + 8)  = make_float4(acc[8], acc[9], acc[10], acc[11]);
    *(float4*)(d + 12) = make_float4(acc[12], acc[13], acc[14], acc[15]);
  }
  __syncthreads();
  // preload mids
  float mreg[64];
  #pragma unroll
  for (int k0 = 0; k0 < 64; k0 += 4) {
    float4 v = *(const float4*)(hrow + k0);
    mreg[k0] = v.x; mreg[k0+1] = v.y; mreg[k0+2] = v.z; mreg[k0+3] = v.w;
  }
  // stage B: out[w16+j] = relu(b2 + sum_c1 w2t[c1][w16+j] * mid[c1])
  float out[16];
  #pragma unroll
  for (int j = 0; j < 16; j++) out[j] = b2v[w16 + j];
  #pragma unroll
  for (int k = 0; k < 64; k++) {
    const float* wr = wl + k * 64 + w16;   // broadcast
    float mv = mreg[k];
    #pragma unroll
    for (int j = 0; j < 16; j++) out[j] = fmaf(wr[j], mv, out[j]);
  }
  bool act = (rbase + lane) < NN;
  #pragma unroll
  for (int j = 0; j < 16; j++) out[j] = act ? fmaxf(out[j], 0.f) : 0.f;
  if (act) {
    float4* dst = (float4*)(h2 + (size_t)(rbase + lane) * 64 + w16);
    dst[0] = make_float4(out[0], out[1], out[2], out[3]);
    dst[1] = make_float4(out[4], out[5], out[6], out[7]);
    dst[2] = make_float4(out[8], out[9], out[10], out[11]);
    dst[3] = make_float4(out[12], out[13], out[14], out[15]);
  }
  // BN partial stats: wave reduce over rows (lanes), lane0 atomics to 1-of-32 copies
  int cp = (blockIdx.x & 31) * 128;
  #pragma unroll
  for (int j = 0; j < 16; j++) {
    float s = out[j], q = s * s;
    #pragma unroll
    for (int mm = 1; mm < 64; mm <<= 1) { s += __shfl_xor(s, mm); q += __shfl_xor(q, mm); }
    if (lane == 0) {
      atomicAdd(&bnsq[cp + w16 + j], s);
      atomicAdd(&bnsq[cp + 64 + w16 + j], q);
    }
  }
}

__global__ __launch_bounds__(64) void k_bnfin(const float* __restrict__ bnsq,
                                              const float* __restrict__ gamma, const float* __restrict__ beta,
                                              int layer, float* __restrict__ scs, float* __restrict__ shs) {
  int c = threadIdx.x;
  if (c >= 64) return;
  const float* sl = bnsq + (size_t)layer * 4096;
  float s = 0.f, q = 0.f;
  for (int cp = 0; cp < 32; cp++) { s += sl[cp * 128 + c]; q += sl[cp * 128 + 64 + c]; }
  float mu = s * (1.0f / NN);
  float var = q * (1.0f / NN) - mu * mu;
  float r = rsqrtf(var + 1e-5f);
  float g = gamma[layer * 64 + c] * r;
  scs[layer * 64 + c] = g;
  shs[layer * 64 + c] = beta[layer * 64 + c] - mu * g;
}

// ---- pool: BN+relu on the fly; batch sorted -> contiguous ranges ----
__global__ __launch_bounds__(256) void k_pool2(const float* __restrict__ h2, const float* __restrict__ sc,
                                               const float* __restrict__ sh, const int* __restrict__ gstart,
                                               float* __restrict__ pooled) {
  int g = blockIdx.x >> 2, sub = blockIdx.x & 3;
  int s = gstart[g], e = gstart[g + 1];
  int c = threadIdx.x & 63, rg = threadIdx.x >> 6;
  float scv = sc[c], shv = sh[c];
  float acc = 0.f;
  for (int r = s + sub * 4 + rg; r < e; r += 16)
    acc += fmaxf(fmaf(h2[(size_t)r * 64 + c], scv, shv), 0.f);
  __shared__ float ls[256];
  ls[threadIdx.x] = acc;
  __syncthreads();
  if (rg == 0) {
    float v = ls[c] + ls[64 + c] + ls[128 + c] + ls[192 + c];
    atomicAdd(&pooled[g * 64 + c], v);
  }
}

__global__ __launch_bounds__(128) void k_head(const float* __restrict__ pooled, const int* __restrict__ gstart,
                                              const float* __restrict__ hw1, const float* __restrict__ hb1,
                                              const float* __restrict__ hw2, const float* __restrict__ hb2,
                                              float* __restrict__ out) {
  __shared__ float p[64];
  __shared__ float z[128];
  int g = blockIdx.x, t = threadIdx.x;
  if (t < 64) {
    int cn = gstart[g + 1] - gstart[g];
    float inv = 1.0f / (float)(cn > 0 ? cn : 1);
    p[t] = pooled[g * 64 + t] * inv;
  }
  __syncthreads();
  float a = hb1[t];
  #pragma unroll
  for (int k = 0; k < 64; k++) a = fmaf(hw1[t * 64 + k], p[k], a);
  z[t] = fmaxf(a, 0.f);
  __syncthreads();
  if (t < OUTC) {
    float b = hb2[t];
    #pragma unroll
    for (int k = 0; k < 128; k++) b = fmaf(hw2[t * 128 + k], z[k], b);
    out[g * OUTC + t] = b;
  }
}

extern "C" void kernel_launch(void* const* d_in, const int* in_sizes, int n_in,
                              void* d_out, int out_size, void* d_ws, size_t ws_size,
                              hipStream_t stream) {
  const float* x_f   = (const float*)d_in[0];
  const int*   ei    = (const int*)d_in[1];
  const float* eattr = (const float*)d_in[2];
  const int*   batch = (const int*)d_in[3];
  const float* l0_ew = (const float*)d_in[4];
  const float* l0_eb = (const float*)d_in[5];
  const float* l0_w1 = (const float*)d_in[6];
  const float* l0_b1 = (const float*)d_in[7];
  const float* l0_w2 = (const float*)d_in[8];
  const float* l0_b2 = (const float*)d_in[9];
  const float* ew    = (const float*)d_in[10];
  const float* eb    = (const float*)d_in[11];
  const float* w1    = (const float*)d_in[12];
  const float* b1    = (const float*)d_in[13];
  const float* w2    = (const float*)d_in[14];
  const float* b2    = (const float*)d_in[15];
  const float* bng   = (const float*)d_in[16];
  const float* bnb   = (const float*)d_in[17];
  const float* hw1   = (const float*)d_in[18];
  const float* hb1   = (const float*)d_in[19];
  const float* hw2   = (const float*)d_in[20];
  const float* hb2   = (const float*)d_in[21];
  const int* esrc = ei;
  const int* edst = ei + NE;

  char* wsb = (char*)d_ws;
  size_t off = 0;
  auto A = [&](size_t bytes) -> void* {
    void* p = wsb + off;
    off = (off + bytes + 255) & ~(size_t)255;
    return p;
  };
  int*   csrc = (int*)A((size_t)(NE + 16) * 4);
  int*   offs = (int*)A((size_t)NN * 4);
  int*   deg  = (int*)A((size_t)NN * 4);
  int*   cur  = (int*)A((size_t)NN * 4);
  int2*  odeg = (int2*)A((size_t)NN * 8);
  int*   bsum = (int*)A(128 * 4);
  int*   gst  = (int*)A((NG + 1) * 4);
  float* xpad = (float*)A((size_t)NN * 64 * 4);
  float* hpre = (float*)A((size_t)NN * 64 * 4);
  float* h2   = (float*)A((size_t)NN * 64 * 4);
  float* bnsq = (float*)A(4 * 32 * 128 * 4);   // [layer][copy0..31][sum64|sq64]
  float* scs  = (float*)A(4 * 64 * 4);
  float* shs  = (float*)A(4 * 64 * 4);
  float* pooled = (float*)A((size_t)NG * 64 * 4);
  float* w2t  = (float*)A(4 * 4096 * 4);
  float* w1t  = (float*)A(4 * 4096 * 4);
  unsigned* ewmf = (unsigned*)A(2048 * 4);  // MFMA-layout f16 edge weights, 4 layers
  float* ebp  = (float*)A(256 * 4);         // padded edge biases, 4 layers
  unsigned* e16 = (unsigned*)A(((size_t)NE + 16) * 32);  // f16 eattr, CSR order, 8 dwords/edge

  hipMemsetAsync(deg, 0, (size_t)NN * 4, stream);
  hipMemsetAsync(bnsq, 0, 4 * 32 * 128 * 4, stream);
  hipMemsetAsync(pooled, 0, (size_t)NG * 64 * 4, stream);
  hipMemsetAsync(csrc + NE, 0, 16 * 4, stream);            // pad: safe src idx for tail chunks
  hipMemsetAsync((char*)e16 + (size_t)NE * 32, 0, 16 * 32, stream);  // pad: clean A-frag tail

  k_tr<<<64, 256, 0, stream>>>(l0_w2, w2, w2t);
  k_tr1<<<64, 256, 0, stream>>>(l0_w1, w1, w1t);
  k_wprep<<<8, 256, 0, stream>>>(l0_ew, l0_eb, ew, eb, ewmf, ebp);
  k_xpad<<<(NN * 64 + 255) / 256, 256, 0, stream>>>(x_f, xpad);
  k_gstart<<<(NN + 255) / 256, 256, 0, stream>>>(batch, gst);

  k_deg<<<(NE + 255) / 256, 256, 0, stream>>>(edst, deg);
  k_scan1<<<98, 1024, 0, stream>>>(deg, offs, bsum);
  k_scan2<<<1, 128, 0, stream>>>(bsum, 98);
  k_scan3<<<(NN + 255) / 256, 256, 0, stream>>>(offs, bsum, deg, cur, odeg);
  k_fillcast<<<(NE + 255) / 256, 256, 0, stream>>>(esrc, edst, cur, (const float4*)eattr,
                                                   csrc, (uint4*)e16);

  const int nodeBlocks = (NN * 64 + 255) / 256;
  const int rowBlocks = (NN + 63) / 64;

  // ---- layer 0 (padded to C=64; BN=false) ----
  k_edgeH<false><<<nodeBlocks, 256, 0, stream>>>(csrc, odeg, xpad, nullptr, nullptr,
                                                 e16, ewmf, ebp, hpre);
  k_mlp<32><<<rowBlocks, 256, 0, stream>>>(hpre, w1t, l0_b1, w2t, l0_b2, h2, bnsq + 0);
  k_bnfin<<<1, 64, 0, stream>>>(bnsq, bng, bnb, 0, scs, shs);

  // ---- layers 1..3: gather from h2 with fused BN(prev)+relu ----
  for (int i = 0; i < 3; i++) {
    k_edgeH<true><<<nodeBlocks, 256, 0, stream>>>(csrc, odeg, h2,
                                                  scs + i * 64, shs + i * 64,
                                                  e16, ewmf + (size_t)(i + 1) * 512, ebp + (i + 1) * 64, hpre);
    k_mlp<64><<<rowBlocks, 256, 0, stream>>>(hpre, w1t + (size_t)(i + 1) * 4096, b1 + (size_t)i * 64,
                                             w2t + (size_t)(i + 1) * 4096, b2 + (size_t)i * 64,
                                             h2, bnsq + (size_t)(i + 1) * 4096);
    k_bnfin<<<1, 64, 0, stream>>>(bnsq, bng, bnb, i + 1, scs, shs);
  }

  // ---- pool (applies BN layer 3) + head ----
  k_pool2<<<NG * 4, 256, 0, stream>>>(h2, scs + 3 * 64, shs + 3 * 64, gst, pooled);
  k_head<<<NG, 128, 0, stream>>>(pooled, gst, hw1, hb1, hw2, hb2, (float*)d_out);
}

// Round 6
// 1085.084 us; speedup vs baseline: 3.2126x; 1.0223x over previous
//
#include <hip/hip_runtime.h>
#include <hip/hip_fp16.h>

// Problem constants
#define NN 100000
#define NE 1600000
#define DIN 32
#define DE 16
#define HC 64
#define NL 4
#define MHC 128
#define OUTC 10
#define NG 128

typedef _Float16 half4_t __attribute__((ext_vector_type(4)));
typedef float f32x4 __attribute__((ext_vector_type(4)));

// ---- CSR build ----
__global__ __launch_bounds__(256) void k_deg(const int* __restrict__ dst, int* __restrict__ deg) {
  int e = blockIdx.x * 256 + threadIdx.x;
  if (e < NE) atomicAdd(&deg[dst[e]], 1);
}

__global__ __launch_bounds__(1024) void k_scan1(const int* __restrict__ deg, int* __restrict__ offs, int* __restrict__ bsum) {
  __shared__ int s[1024];
  int t = threadIdx.x;
  int i = blockIdx.x * 1024 + t;
  int v = (i < NN) ? deg[i] : 0;
  s[t] = v; __syncthreads();
  for (int d = 1; d < 1024; d <<= 1) {
    int x = 0;
    if (t >= d) x = s[t - d];
    __syncthreads();
    if (t >= d) s[t] += x;
    __syncthreads();
  }
  if (i < NN) offs[i] = s[t] - v;
  if (t == 1023) bsum[blockIdx.x] = s[t];
}

__global__ __launch_bounds__(128) void k_scan2(int* __restrict__ bsum, int nb) {
  __shared__ int s[128];
  int t = threadIdx.x;
  int v = (t < nb) ? bsum[t] : 0;
  s[t] = v; __syncthreads();
  for (int d = 1; d < 128; d <<= 1) {
    int x = 0;
    if (t >= d) x = s[t - d];
    __syncthreads();
    if (t >= d) s[t] += x;
    __syncthreads();
  }
  if (t < nb) bsum[t] = s[t] - v;
}

// also builds odeg = (start, deg) int2
__global__ __launch_bounds__(256) void k_scan3(int* __restrict__ offs, const int* __restrict__ bsum,
                                               const int* __restrict__ deg,
                                               int* __restrict__ cur, int2* __restrict__ odeg) {
  int i = blockIdx.x * 256 + threadIdx.x;
  if (i < NN) {
    int o = offs[i] + bsum[i >> 10];
    offs[i] = o;
    cur[i] = o;
    odeg[i] = make_int2(o, deg[i]);
  }
}

// ---- fused fill + cast: one pass over edges (coalesced reads of src/dst/eattr),
//      scatter-write csrc (4B) + e16 (32B, single 64B line) at CSR position. ----
__global__ __launch_bounds__(256) void k_fillcast(const int* __restrict__ src, const int* __restrict__ dst,
                                                  int* __restrict__ cur,
                                                  const float4* __restrict__ eattr4,
                                                  int* __restrict__ csrc, uint4* __restrict__ e16) {
  int e = blockIdx.x * 256 + threadIdx.x;
  if (e >= NE) return;
  int d = dst[e];
  float4 a0 = eattr4[(size_t)e * 4 + 0];
  float4 a1 = eattr4[(size_t)e * 4 + 1];
  float4 a2 = eattr4[(size_t)e * 4 + 2];
  float4 a3 = eattr4[(size_t)e * 4 + 3];
  int s = src[e];
  int pos = atomicAdd(&cur[d], 1);
  __half2 h0 = __floats2half2_rn(a0.x, a0.y), h1 = __floats2half2_rn(a0.z, a0.w);
  __half2 h2 = __floats2half2_rn(a1.x, a1.y), h3 = __floats2half2_rn(a1.z, a1.w);
  __half2 h4 = __floats2half2_rn(a2.x, a2.y), h5 = __floats2half2_rn(a2.z, a2.w);
  __half2 h6 = __floats2half2_rn(a3.x, a3.y), h7 = __floats2half2_rn(a3.z, a3.w);
  uint4 o0 = make_uint4(*(unsigned*)&h0, *(unsigned*)&h1, *(unsigned*)&h2, *(unsigned*)&h3);
  uint4 o1 = make_uint4(*(unsigned*)&h4, *(unsigned*)&h5, *(unsigned*)&h6, *(unsigned*)&h7);
  csrc[pos] = s;
  e16[(size_t)pos * 2 + 0] = o0;
  e16[(size_t)pos * 2 + 1] = o1;
}

// ---- edge weights -> MFMA B-fragment layout [4 layers][4 grp][64 lane][2 dw]
//      + padded biases [4][64] ----
__global__ __launch_bounds__(256) void k_wprep(const float* __restrict__ l0ew, const float* __restrict__ l0eb,
                                               const float* __restrict__ ew, const float* __restrict__ eb,
                                               unsigned* __restrict__ ewmf, float* __restrict__ ebp) {
  int i = blockIdx.x * 256 + threadIdx.x;
  if (i < 2048) {
    int j = i & 1;           // dword within lane fragment
    int l = (i >> 1) & 63;   // lane
    int g = (i >> 7) & 3;    // channel group
    int L = i >> 9;          // layer
    int ch = 16 * g + (l & 15);
    int k0 = 4 * (l >> 4) + 2 * j;
    float a, b;
    if (L == 0) {
      a = (ch < 32) ? l0ew[ch * 16 + k0] : 0.f;
      b = (ch < 32) ? l0ew[ch * 16 + k0 + 1] : 0.f;
    } else {
      a = ew[(size_t)(L - 1) * 1024 + ch * 16 + k0];
      b = ew[(size_t)(L - 1) * 1024 + ch * 16 + k0 + 1];
    }
    __half2 h = __floats2half2_rn(a, b);
    ewmf[i] = *(unsigned*)&h;
  }
  if (i < 256) {
    int L = i >> 6, c = i & 63;
    ebp[i] = (L == 0) ? ((c < 32) ? l0eb[c] : 0.f) : eb[(size_t)(L - 1) * 64 + c];
  }
}

// ---- graph boundaries (batch sorted) ----
__global__ __launch_bounds__(256) void k_gstart(const int* __restrict__ batch, int* __restrict__ gstart) {
  int i = blockIdx.x * 256 + threadIdx.x;
  if (i >= NN) return;
  int b = batch[i];
  int bp = (i == 0) ? -1 : batch[i - 1];
  for (int g = bp + 1; g <= b; g++) gstart[g] = i;
  if (i == NN - 1)
    for (int g = b + 1; g <= NG; g++) gstart[g] = NN;
}

// ---- w2 transpose: w2t[mat][c1][c2] = w2[mat][c2][c1] ----
__global__ __launch_bounds__(256) void k_tr(const float* __restrict__ l0w2, const float* __restrict__ w2,
                                            float* __restrict__ w2t) {
  int id = blockIdx.x * 256 + threadIdx.x;
  int mat = id >> 12;
  int j = id & 4095;
  int c1 = j >> 6, c2 = j & 63;
  const float* s = (mat == 0) ? l0w2 : (w2 + (size_t)(mat - 1) * 4096);
  w2t[mat * 4096 + j] = s[c2 * 64 + c1];
}

// ---- w1 transpose + pad: w1t[L][k][c1]; layer0 k>=32 zero-padded ----
__global__ __launch_bounds__(256) void k_tr1(const float* __restrict__ l0w1, const float* __restrict__ w1,
                                             float* __restrict__ w1t) {
  int id = blockIdx.x * 256 + threadIdx.x;
  if (id >= 4 * 4096) return;
  int L = id >> 12, j = id & 4095;
  int k = j >> 6, c = j & 63;
  float v;
  if (L == 0) v = (k < 32) ? l0w1[c * 32 + k] : 0.f;
  else v = w1[(size_t)(L - 1) * 4096 + c * 64 + k];
  w1t[id] = v;
}

// ---- x -> f16 channel-interleaved gather layout xg16[row][(c&15)*4 + (c>>4)],
//      ch>=32 zero (layer-0 padding). R5 lesson: edgeH is gather-fetch-bound;
//      f16 + interleave halves bytes and turns 16 gather loads/chunk into 4. ----
__global__ __launch_bounds__(256) void k_xpad16(const float* __restrict__ x, _Float16* __restrict__ xg16) {
  int i = blockIdx.x * 256 + threadIdx.x;   // over NN*64
  if (i >= NN * 64) return;
  int row = i >> 6, c = i & 63;
  float v = (c < 32) ? x[(size_t)row * 32 + c] : 0.f;
  xg16[(size_t)row * 64 + (c & 15) * 4 + (c >> 4)] = (_Float16)v;
}

// ---- BN+relu applied once per layer: h2 (f32) -> xg16 (f16, interleaved).
//      Removes per-edge BN math from edgeH and halves its gather traffic. ----
__global__ __launch_bounds__(256) void k_bnapply(const float* __restrict__ h2,
                                                 const float* __restrict__ sc, const float* __restrict__ sh,
                                                 _Float16* __restrict__ xg16) {
  int i = blockIdx.x * 256 + threadIdx.x;   // over NN*64
  if (i >= NN * 64) return;
  int row = i >> 6, c = i & 63;
  float v = fmaxf(fmaf(h2[i], sc[c], sh[c]), 0.f);
  xg16[(size_t)row * 64 + (c & 15) * 4 + (c >> 4)] = (_Float16)v;
}

// ---- edge aggregation, v6: MFMA edge-linear + f16 interleaved x-gather.
//      Per 16-edge chunk: 4x mfma_f32_16x16x16f16 for the edge transform;
//      4 dwordx2 row-gathers (one per edge owned by this lane quarter, 128B
//      rows). xg16 is pre-BN-relu'd, so no BN math here. Wave per node. ----
__global__ __launch_bounds__(256) void k_edgeH(
    const int* __restrict__ csrc, const int2* __restrict__ odeg,
    const _Float16* __restrict__ xg16,
    const unsigned* __restrict__ e16,
    const unsigned* __restrict__ ewmf, const float* __restrict__ ebf,
    float* __restrict__ hpre)
{
  int gt = blockIdx.x * 256 + threadIdx.x;
  int node = gt >> 6;
  if (node >= NN) return;
  int c = threadIdx.x & 63;
  int m = c & 15;    // A row (edge-in-chunk) / ch-in-group
  int qv = c >> 4;   // lane quarter

  half4_t bf[4];
  #pragma unroll
  for (int g = 0; g < 4; g++) {
    uint2 wv = *(const uint2*)(ewmf + (size_t)(g * 64 + c) * 2);
    bf[g] = __builtin_bit_cast(half4_t, wv);
  }
  float bb[4];
  #pragma unroll
  for (int g = 0; g < 4; g++) bb[g] = ebf[16 * g + m];
  int2 od = odeg[node];
  int start = od.x, n = od.y;
  float acc[4] = {0.f, 0.f, 0.f, 0.f};

  for (int base = 0; base < n; base += 16) {
    int cn = n - base;           // valid edges this chunk (may exceed 16)
    int p = start + base;
    // A fragment: coalesced 512B across the wave
    uint2 av = *(const uint2*)(e16 + (size_t)(p + m) * 8 + qv * 2);
    half4_t af = __builtin_bit_cast(half4_t, av);
    // edge linear: D[edge][ch] = A x B + bias
    f32x4 d0, d1, d2, d3;
    {
      f32x4 ci;
      ci[0] = bb[0]; ci[1] = bb[0]; ci[2] = bb[0]; ci[3] = bb[0];
      d0 = __builtin_amdgcn_mfma_f32_16x16x16f16(af, bf[0], ci, 0, 0, 0);
      ci[0] = bb[1]; ci[1] = bb[1]; ci[2] = bb[1]; ci[3] = bb[1];
      d1 = __builtin_amdgcn_mfma_f32_16x16x16f16(af, bf[1], ci, 0, 0, 0);
      ci[0] = bb[2]; ci[1] = bb[2]; ci[2] = bb[2]; ci[3] = bb[2];
      d2 = __builtin_amdgcn_mfma_f32_16x16x16f16(af, bf[2], ci, 0, 0, 0);
      ci[0] = bb[3]; ci[1] = bb[3]; ci[2] = bb[3]; ci[3] = bb[3];
      d3 = __builtin_amdgcn_mfma_f32_16x16x16f16(af, bf[3], ci, 0, 0, 0);
    }
    // src broadcast: lane holds csrc[p+m]; my 4 edges are 4*qv+r
    int sidx = csrc[p + m];
    #pragma unroll
    for (int r = 0; r < 4; r++) {
      int s = __shfl(sidx, 4 * qv + r);
      bool valid = (4 * qv + r) < cn;
      // lane's 4 channels {m,m+16,m+32,m+48} of row s: 8B contiguous
      uint2 xv = *(const uint2*)(xg16 + (size_t)s * 64 + m * 4);
      half4_t hx = __builtin_bit_cast(half4_t, xv);
      #pragma unroll
      for (int g = 0; g < 4; g++) {
        float xs = (float)hx[g];
        float el = (r == 0) ? ((g == 0) ? d0[0] : (g == 1) ? d1[0] : (g == 2) ? d2[0] : d3[0])
                 : (r == 1) ? ((g == 0) ? d0[1] : (g == 1) ? d1[1] : (g == 2) ? d2[1] : d3[1])
                 : (r == 2) ? ((g == 0) ? d0[2] : (g == 1) ? d1[2] : (g == 2) ? d2[2] : d3[2])
                 :            ((g == 0) ? d0[3] : (g == 1) ? d1[3] : (g == 2) ? d2[3] : d3[3]);
        float v = fmaxf(xs + el, 0.f);
        acc[g] += valid ? v : 0.f;
      }
    }
  }
  // reduce across lane quarters (edge split)
  #pragma unroll
  for (int g = 0; g < 4; g++) {
    acc[g] += __shfl_xor(acc[g], 16);
    acc[g] += __shfl_xor(acc[g], 32);
  }
  float xself = (float)xg16[(size_t)node * 64 + (c & 15) * 4 + (c >> 4)];
  float sum = (qv == 0) ? acc[0] : (qv == 1) ? acc[1] : (qv == 2) ? acc[2] : acc[3];
  hpre[(size_t)node * 64 + c] = xself + sum;
}

// ---- fused node MLP + BN-stats epilogue: weights staged in LDS. ----
template<int CIN>
__global__ __launch_bounds__(256) void k_mlp(
    const float* __restrict__ hpre,
    const float* __restrict__ w1tf, const float* __restrict__ b1f,
    const float* __restrict__ w2tf, const float* __restrict__ b2v,
    float* __restrict__ h2, float* __restrict__ bnsq)
{
  __shared__ float wl[64 * 64];   // weight tile (16KB), w1 then w2
  __shared__ float hl[64 * 65];   // act tile, pad 65 -> 2-way bank = free
  int tid = threadIdx.x;
  int wid = __builtin_amdgcn_readfirstlane(tid >> 6);
  int lane = tid & 63;
  int rbase = blockIdx.x * 64;
  {
    const float4* s = (const float4*)w1tf;
    float4* d = (float4*)wl;
    #pragma unroll
    for (int q = 0; q < 4; q++) d[tid + 256 * q] = s[tid + 256 * q];
  }
  {
    int r = tid >> 2, ko = (tid & 3) * 16;
    int rg = rbase + r;
    float4 v0, v1, v2, v3;
    if (rg < NN) {
      const float4* src = (const float4*)(hpre + (size_t)rg * 64 + ko);
      v0 = src[0]; v1 = src[1]; v2 = src[2]; v3 = src[3];
    } else {
      v0 = v1 = v2 = v3 = make_float4(0.f, 0.f, 0.f, 0.f);
    }
    float* d = hl + r * 65 + ko;
    *(float4*)(d + 0) = v0; *(float4*)(d + 4) = v1;
    *(float4*)(d + 8) = v2; *(float4*)(d + 12) = v3;
  }
  float4 w2r[4];
  {
    const float4* s = (const float4*)w2tf;
    #pragma unroll
    for (int q = 0; q < 4; q++) w2r[q] = s[tid + 256 * q];
  }
  __syncthreads();
  int w16 = wid * 16;
  const float* hrow = hl + lane * 65;
  float hreg[CIN];
  #pragma unroll
  for (int k0 = 0; k0 < CIN; k0 += 4) {
    float4 v = *(const float4*)(hrow + k0);
    hreg[k0] = v.x; hreg[k0+1] = v.y; hreg[k0+2] = v.z; hreg[k0+3] = v.w;
  }
  float acc[16];
  #pragma unroll
  for (int j = 0; j < 16; j++) acc[j] = b1f[w16 + j];
  #pragma unroll
  for (int k = 0; k < CIN; k++) {
    const float* wr = wl + k * 64 + w16;   // wave-uniform LDS -> broadcast
    float hv = hreg[k];
    #pragma unroll
    for (int j = 0; j < 16; j++) acc[j] = fmaf(wr[j], hv, acc[j]);
  }
  #pragma unroll
  for (int j = 0; j < 16; j++) acc[j] = fmaxf(acc[j], 0.f);
  __syncthreads();
  {
    float4* d = (float4*)wl;
    #pragma unroll
    for (int q = 0; q < 4; q++) d[tid + 256 * q] = w2r[q];
  }
  {
    float* d = hl + lane * 65 + w16;
    *(float4*)(d + 0)  = make_float4(acc[0], acc[1], acc[2], acc[3]);
    *(float4*)(d + 4)  = make_float4(acc[4], acc[5], acc[6], acc[7]);
    *(float4*)(d + 8)  = make_float4(acc[8], acc[9], acc[10], acc[11]);
    *(float4*)(d + 12) = make_float4(acc[12], acc[13], acc[14], acc[15]);
  }
  __syncthreads();
  float mreg[64];
  #pragma unroll
  for (int k0 = 0; k0 < 64; k0 += 4) {
    float4 v = *(const float4*)(hrow + k0);
    mreg[k0] = v.x; mreg[k0+1] = v.y; mreg[k0+2] = v.z; mreg[k0+3] = v.w;
  }
  float out[16];
  #pragma unroll
  for (int j = 0; j < 16; j++) out[j] = b2v[w16 + j];
  #pragma unroll
  for (int k = 0; k < 64; k++) {
    const float* wr = wl + k * 64 + w16;   // broadcast
    float mv = mreg[k];
    #pragma unroll
    for (int j = 0; j < 16; j++) out[j] = fmaf(wr[j], mv, out[j]);
  }
  bool act = (rbase + lane) < NN;
  #pragma unroll
  for (int j = 0; j < 16; j++) out[j] = act ? fmaxf(out[j], 0.f) : 0.f;
  if (act) {
    float4* dst = (float4*)(h2 + (size_t)(rbase + lane) * 64 + w16);
    dst[0] = make_float4(out[0], out[1], out[2], out[3]);
    dst[1] = make_float4(out[4], out[5], out[6], out[7]);
    dst[2] = make_float4(out[8], out[9], out[10], out[11]);
    dst[3] = make_float4(out[12], out[13], out[14], out[15]);
  }
  int cp = (blockIdx.x & 31) * 128;
  #pragma unroll
  for (int j = 0; j < 16; j++) {
    float s = out[j], q = s * s;
    #pragma unroll
    for (int mm = 1; mm < 64; mm <<= 1) { s += __shfl_xor(s, mm); q += __shfl_xor(q, mm); }
    if (lane == 0) {
      atomicAdd(&bnsq[cp + w16 + j], s);
      atomicAdd(&bnsq[cp + 64 + w16 + j], q);
    }
  }
}

__global__ __launch_bounds__(64) void k_bnfin(const float* __restrict__ bnsq,
                                              const float* __restrict__ gamma, const float* __restrict__ beta,
                                              int layer, float* __restrict__ scs, float* __restrict__ shs) {
  int c = threadIdx.x;
  if (c >= 64) return;
  const float* sl = bnsq + (size_t)layer * 4096;
  float s = 0.f, q = 0.f;
  for (int cp = 0; cp < 32; cp++) { s += sl[cp * 128 + c]; q += sl[cp * 128 + 64 + c]; }
  float mu = s * (1.0f / NN);
  float var = q * (1.0f / NN) - mu * mu;
  float r = rsqrtf(var + 1e-5f);
  float g = gamma[layer * 64 + c] * r;
  scs[layer * 64 + c] = g;
  shs[layer * 64 + c] = beta[layer * 64 + c] - mu * g;
}

// ---- pool: BN+relu on the fly; batch sorted -> contiguous ranges ----
__global__ __launch_bounds__(256) void k_pool2(const float* __restrict__ h2, const float* __restrict__ sc,
                                               const float* __restrict__ sh, const int* __restrict__ gstart,
                                               float* __restrict__ pooled) {
  int g = blockIdx.x >> 2, sub = blockIdx.x & 3;
  int s = gstart[g], e = gstart[g + 1];
  int c = threadIdx.x & 63, rg = threadIdx.x >> 6;
  float scv = sc[c], shv = sh[c];
  float acc = 0.f;
  for (int r = s + sub * 4 + rg; r < e; r += 16)
    acc += fmaxf(fmaf(h2[(size_t)r * 64 + c], scv, shv), 0.f);
  __shared__ float ls[256];
  ls[threadIdx.x] = acc;
  __syncthreads();
  if (rg == 0) {
    float v = ls[c] + ls[64 + c] + ls[128 + c] + ls[192 + c];
    atomicAdd(&pooled[g * 64 + c], v);
  }
}

__global__ __launch_bounds__(128) void k_head(const float* __restrict__ pooled, const int* __restrict__ gstart,
                                              const float* __restrict__ hw1, const float* __restrict__ hb1,
                                              const float* __restrict__ hw2, const float* __restrict__ hb2,
                                              float* __restrict__ out) {
  __shared__ float p[64];
  __shared__ float z[128];
  int g = blockIdx.x, t = threadIdx.x;
  if (t < 64) {
    int cn = gstart[g + 1] - gstart[g];
    float inv = 1.0f / (float)(cn > 0 ? cn : 1);
    p[t] = pooled[g * 64 + t] * inv;
  }
  __syncthreads();
  float a = hb1[t];
  #pragma unroll
  for (int k = 0; k < 64; k++) a = fmaf(hw1[t * 64 + k], p[k], a);
  z[t] = fmaxf(a, 0.f);
  __syncthreads();
  if (t < OUTC) {
    float b = hb2[t];
    #pragma unroll
    for (int k = 0; k < 128; k++) b = fmaf(hw2[t * 128 + k], z[k], b);
    out[g * OUTC + t] = b;
  }
}

extern "C" void kernel_launch(void* const* d_in, const int* in_sizes, int n_in,
                              void* d_out, int out_size, void* d_ws, size_t ws_size,
                              hipStream_t stream) {
  const float* x_f   = (const float*)d_in[0];
  const int*   ei    = (const int*)d_in[1];
  const float* eattr = (const float*)d_in[2];
  const int*   batch = (const int*)d_in[3];
  const float* l0_ew = (const float*)d_in[4];
  const float* l0_eb = (const float*)d_in[5];
  const float* l0_w1 = (const float*)d_in[6];
  const float* l0_b1 = (const float*)d_in[7];
  const float* l0_w2 = (const float*)d_in[8];
  const float* l0_b2 = (const float*)d_in[9];
  const float* ew    = (const float*)d_in[10];
  const float* eb    = (const float*)d_in[11];
  const float* w1    = (const float*)d_in[12];
  const float* b1    = (const float*)d_in[13];
  const float* w2    = (const float*)d_in[14];
  const float* b2    = (const float*)d_in[15];
  const float* bng   = (const float*)d_in[16];
  const float* bnb   = (const float*)d_in[17];
  const float* hw1   = (const float*)d_in[18];
  const float* hb1   = (const float*)d_in[19];
  const float* hw2   = (const float*)d_in[20];
  const float* hb2   = (const float*)d_in[21];
  const int* esrc = ei;
  const int* edst = ei + NE;

  char* wsb = (char*)d_ws;
  size_t off = 0;
  auto A = [&](size_t bytes) -> void* {
    void* p = wsb + off;
    off = (off + bytes + 255) & ~(size_t)255;
    return p;
  };
  int*   csrc = (int*)A((size_t)(NE + 16) * 4);
  int*   offs = (int*)A((size_t)NN * 4);
  int*   deg  = (int*)A((size_t)NN * 4);
  int*   cur  = (int*)A((size_t)NN * 4);
  int2*  odeg = (int2*)A((size_t)NN * 8);
  int*   bsum = (int*)A(128 * 4);
  int*   gst  = (int*)A((NG + 1) * 4);
  _Float16* xg16 = (_Float16*)A((size_t)NN * 64 * 2);  // f16 interleaved gather operand
  float* hpre = (float*)A((size_t)NN * 64 * 4);
  float* h2   = (float*)A((size_t)NN * 64 * 4);
  float* bnsq = (float*)A(4 * 32 * 128 * 4);   // [layer][copy0..31][sum64|sq64]
  float* scs  = (float*)A(4 * 64 * 4);
  float* shs  = (float*)A(4 * 64 * 4);
  float* pooled = (float*)A((size_t)NG * 64 * 4);
  float* w2t  = (float*)A(4 * 4096 * 4);
  float* w1t  = (float*)A(4 * 4096 * 4);
  unsigned* ewmf = (unsigned*)A(2048 * 4);  // MFMA-layout f16 edge weights, 4 layers
  float* ebp  = (float*)A(256 * 4);         // padded edge biases, 4 layers
  unsigned* e16 = (unsigned*)A(((size_t)NE + 16) * 32);  // f16 eattr, CSR order, 8 dwords/edge

  hipMemsetAsync(deg, 0, (size_t)NN * 4, stream);
  hipMemsetAsync(bnsq, 0, 4 * 32 * 128 * 4, stream);
  hipMemsetAsync(pooled, 0, (size_t)NG * 64 * 4, stream);
  hipMemsetAsync(csrc + NE, 0, 16 * 4, stream);            // pad: safe src idx for tail chunks
  hipMemsetAsync((char*)e16 + (size_t)NE * 32, 0, 16 * 32, stream);  // pad: clean A-frag tail

  k_tr<<<64, 256, 0, stream>>>(l0_w2, w2, w2t);
  k_tr1<<<64, 256, 0, stream>>>(l0_w1, w1, w1t);
  k_wprep<<<8, 256, 0, stream>>>(l0_ew, l0_eb, ew, eb, ewmf, ebp);
  k_xpad16<<<(NN * 64 + 255) / 256, 256, 0, stream>>>(x_f, xg16);
  k_gstart<<<(NN + 255) / 256, 256, 0, stream>>>(batch, gst);

  k_deg<<<(NE + 255) / 256, 256, 0, stream>>>(edst, deg);
  k_scan1<<<98, 1024, 0, stream>>>(deg, offs, bsum);
  k_scan2<<<1, 128, 0, stream>>>(bsum, 98);
  k_scan3<<<(NN + 255) / 256, 256, 0, stream>>>(offs, bsum, deg, cur, odeg);
  k_fillcast<<<(NE + 255) / 256, 256, 0, stream>>>(esrc, edst, cur, (const float4*)eattr,
                                                   csrc, (uint4*)e16);

  const int nodeBlocks = (NN * 64 + 255) / 256;
  const int rowBlocks = (NN + 63) / 64;
  const int elemBlocks = (NN * 64 + 255) / 256;

  // ---- layer 0 (padded to C=64) ----
  k_edgeH<<<nodeBlocks, 256, 0, stream>>>(csrc, odeg, xg16, e16, ewmf, ebp, hpre);
  k_mlp<32><<<rowBlocks, 256, 0, stream>>>(hpre, w1t, l0_b1, w2t, l0_b2, h2, bnsq + 0);
  k_bnfin<<<1, 64, 0, stream>>>(bnsq, bng, bnb, 0, scs, shs);

  // ---- layers 1..3: pre-apply BN(prev)+relu -> f16 gather operand ----
  for (int i = 0; i < 3; i++) {
    k_bnapply<<<elemBlocks, 256, 0, stream>>>(h2, scs + i * 64, shs + i * 64, xg16);
    k_edgeH<<<nodeBlocks, 256, 0, stream>>>(csrc, odeg, xg16,
                                            e16, ewmf + (size_t)(i + 1) * 512, ebp + (i + 1) * 64, hpre);
    k_mlp<64><<<rowBlocks, 256, 0, stream>>>(hpre, w1t + (size_t)(i + 1) * 4096, b1 + (size_t)i * 64,
                                             w2t + (size_t)(i + 1) * 4096, b2 + (size_t)i * 64,
                                             h2, bnsq + (size_t)(i + 1) * 4096);
    k_bnfin<<<1, 64, 0, stream>>>(bnsq, bng, bnb, i + 1, scs, shs);
  }

  // ---- pool (applies BN layer 3) + head ----
  k_pool2<<<NG * 4, 256, 0, stream>>>(h2, scs + 3 * 64, shs + 3 * 64, gst, pooled);
  k_head<<<NG, 128, 0, stream>>>(pooled, gst, hw1, hb1, hw2, hb2, (float*)d_out);
}

// Round 7
// 834.909 us; speedup vs baseline: 4.1753x; 1.2996x over previous
//
#include <hip/hip_runtime.h>
#include <hip/hip_fp16.h>

// Problem constants
#define NN 100000
#define NE 1600000
#define DIN 32
#define DE 16
#define HC 64
#define NL 4
#define MHC 128
#define OUTC 10
#define NG 128

typedef _Float16 half4_t __attribute__((ext_vector_type(4)));
typedef float f32x4 __attribute__((ext_vector_type(4)));

// ---- CSR build ----
__global__ __launch_bounds__(256) void k_deg(const int* __restrict__ dst, int* __restrict__ deg) {
  int e = blockIdx.x * 256 + threadIdx.x;
  if (e < NE) atomicAdd(&deg[dst[e]], 1);
}

__global__ __launch_bounds__(1024) void k_scan1(const int* __restrict__ deg, int* __restrict__ offs, int* __restrict__ bsum) {
  __shared__ int s[1024];
  int t = threadIdx.x;
  int i = blockIdx.x * 1024 + t;
  int v = (i < NN) ? deg[i] : 0;
  s[t] = v; __syncthreads();
  for (int d = 1; d < 1024; d <<= 1) {
    int x = 0;
    if (t >= d) x = s[t - d];
    __syncthreads();
    if (t >= d) s[t] += x;
    __syncthreads();
  }
  if (i < NN) offs[i] = s[t] - v;
  if (t == 1023) bsum[blockIdx.x] = s[t];
}

__global__ __launch_bounds__(128) void k_scan2(int* __restrict__ bsum, int nb) {
  __shared__ int s[128];
  int t = threadIdx.x;
  int v = (t < nb) ? bsum[t] : 0;
  s[t] = v; __syncthreads();
  for (int d = 1; d < 128; d <<= 1) {
    int x = 0;
    if (t >= d) x = s[t - d];
    __syncthreads();
    if (t >= d) s[t] += x;
    __syncthreads();
  }
  if (t < nb) bsum[t] = s[t] - v;
}

// also builds odeg = (start, deg) int2
__global__ __launch_bounds__(256) void k_scan3(int* __restrict__ offs, const int* __restrict__ bsum,
                                               const int* __restrict__ deg,
                                               int* __restrict__ cur, int2* __restrict__ odeg) {
  int i = blockIdx.x * 256 + threadIdx.x;
  if (i < NN) {
    int o = offs[i] + bsum[i >> 10];
    offs[i] = o;
    cur[i] = o;
    odeg[i] = make_int2(o, deg[i]);
  }
}

// ---- fused fill + cast: one pass over edges (coalesced reads of src/dst/eattr),
//      scatter-write csrc (4B) + e16 (32B, single 64B line) at CSR position. ----
__global__ __launch_bounds__(256) void k_fillcast(const int* __restrict__ src, const int* __restrict__ dst,
                                                  int* __restrict__ cur,
                                                  const float4* __restrict__ eattr4,
                                                  int* __restrict__ csrc, uint4* __restrict__ e16) {
  int e = blockIdx.x * 256 + threadIdx.x;
  if (e >= NE) return;
  int d = dst[e];
  float4 a0 = eattr4[(size_t)e * 4 + 0];
  float4 a1 = eattr4[(size_t)e * 4 + 1];
  float4 a2 = eattr4[(size_t)e * 4 + 2];
  float4 a3 = eattr4[(size_t)e * 4 + 3];
  int s = src[e];
  int pos = atomicAdd(&cur[d], 1);
  __half2 h0 = __floats2half2_rn(a0.x, a0.y), h1 = __floats2half2_rn(a0.z, a0.w);
  __half2 h2 = __floats2half2_rn(a1.x, a1.y), h3 = __floats2half2_rn(a1.z, a1.w);
  __half2 h4 = __floats2half2_rn(a2.x, a2.y), h5 = __floats2half2_rn(a2.z, a2.w);
  __half2 h6 = __floats2half2_rn(a3.x, a3.y), h7 = __floats2half2_rn(a3.z, a3.w);
  uint4 o0 = make_uint4(*(unsigned*)&h0, *(unsigned*)&h1, *(unsigned*)&h2, *(unsigned*)&h3);
  uint4 o1 = make_uint4(*(unsigned*)&h4, *(unsigned*)&h5, *(unsigned*)&h6, *(unsigned*)&h7);
  csrc[pos] = s;
  e16[(size_t)pos * 2 + 0] = o0;
  e16[(size_t)pos * 2 + 1] = o1;
}

// ---- edge weights -> MFMA B-fragment layout [4 layers][4 grp][64 lane][2 dw]
//      + padded biases [4][64] ----
__global__ __launch_bounds__(256) void k_wprep(const float* __restrict__ l0ew, const float* __restrict__ l0eb,
                                               const float* __restrict__ ew, const float* __restrict__ eb,
                                               unsigned* __restrict__ ewmf, float* __restrict__ ebp) {
  int i = blockIdx.x * 256 + threadIdx.x;
  if (i < 2048) {
    int j = i & 1;           // dword within lane fragment
    int l = (i >> 1) & 63;   // lane
    int g = (i >> 7) & 3;    // channel group
    int L = i >> 9;          // layer
    int ch = 16 * g + (l & 15);
    int k0 = 4 * (l >> 4) + 2 * j;
    float a, b;
    if (L == 0) {
      a = (ch < 32) ? l0ew[ch * 16 + k0] : 0.f;
      b = (ch < 32) ? l0ew[ch * 16 + k0 + 1] : 0.f;
    } else {
      a = ew[(size_t)(L - 1) * 1024 + ch * 16 + k0];
      b = ew[(size_t)(L - 1) * 1024 + ch * 16 + k0 + 1];
    }
    __half2 h = __floats2half2_rn(a, b);
    ewmf[i] = *(unsigned*)&h;
  }
  if (i < 256) {
    int L = i >> 6, c = i & 63;
    ebp[i] = (L == 0) ? ((c < 32) ? l0eb[c] : 0.f) : eb[(size_t)(L - 1) * 64 + c];
  }
}

// ---- node-MLP weights -> MFMA B-fragments, f16.
//      wB[L][mat][kb][cg][lane][j]: value pair = W[c][k0], W[c][k0+1]
//      with c = cg*16+(lane&15), k0 = kb*16 + 4*(lane>>4) + 2*j.
//      mat0 = w1 (layer0: [64][32], k>=32 zero), mat1 = w2 ([64][64]). ----
__global__ __launch_bounds__(256) void k_wmlp(const float* __restrict__ l0w1, const float* __restrict__ w1,
                                              const float* __restrict__ l0w2, const float* __restrict__ w2,
                                              unsigned* __restrict__ wB) {
  int id = blockIdx.x * 256 + threadIdx.x;
  if (id >= 16384) return;
  int j = id & 1;
  int l = (id >> 1) & 63;
  int cg = (id >> 7) & 3;
  int kb = (id >> 9) & 3;
  int mat = (id >> 11) & 1;
  int L = (id >> 12) & 3;
  int k0 = kb * 16 + 4 * (l >> 4) + 2 * j;
  int c = cg * 16 + (l & 15);
  float a, b;
  if (mat == 0) {
    if (L == 0) {
      a = (k0 < 32) ? l0w1[c * 32 + k0] : 0.f;
      b = (k0 + 1 < 32) ? l0w1[c * 32 + k0 + 1] : 0.f;
    } else {
      a = w1[(size_t)(L - 1) * 4096 + c * 64 + k0];
      b = w1[(size_t)(L - 1) * 4096 + c * 64 + k0 + 1];
    }
  } else {
    if (L == 0) {
      a = l0w2[c * 64 + k0];
      b = l0w2[c * 64 + k0 + 1];
    } else {
      a = w2[(size_t)(L - 1) * 4096 + c * 64 + k0];
      b = w2[(size_t)(L - 1) * 4096 + c * 64 + k0 + 1];
    }
  }
  __half2 h = __floats2half2_rn(a, b);
  wB[id] = *(unsigned*)&h;
}

// ---- graph boundaries (batch sorted) ----
__global__ __launch_bounds__(256) void k_gstart(const int* __restrict__ batch, int* __restrict__ gstart) {
  int i = blockIdx.x * 256 + threadIdx.x;
  if (i >= NN) return;
  int b = batch[i];
  int bp = (i == 0) ? -1 : batch[i - 1];
  for (int g = bp + 1; g <= b; g++) gstart[g] = i;
  if (i == NN - 1)
    for (int g = b + 1; g <= NG; g++) gstart[g] = NN;
}

// ---- x -> f16 channel-interleaved gather layout xg16[row][(c&15)*4 + (c>>4)],
//      ch>=32 zero (layer-0 padding). ----
__global__ __launch_bounds__(256) void k_xpad16(const float* __restrict__ x, _Float16* __restrict__ xg16) {
  int i = blockIdx.x * 256 + threadIdx.x;   // over NN*64
  if (i >= NN * 64) return;
  int row = i >> 6, c = i & 63;
  float v = (c < 32) ? x[(size_t)row * 32 + c] : 0.f;
  xg16[(size_t)row * 64 + (c & 15) * 4 + (c >> 4)] = (_Float16)v;
}

// ---- BN+relu applied once per layer: h2 (f32) -> xg16 (f16, interleaved). ----
__global__ __launch_bounds__(256) void k_bnapply(const float* __restrict__ h2,
                                                 const float* __restrict__ sc, const float* __restrict__ sh,
                                                 _Float16* __restrict__ xg16) {
  int i = blockIdx.x * 256 + threadIdx.x;   // over NN*64
  if (i >= NN * 64) return;
  int row = i >> 6, c = i & 63;
  float v = fmaxf(fmaf(h2[i], sc[c], sh[c]), 0.f);
  xg16[(size_t)row * 64 + (c & 15) * 4 + (c >> 4)] = (_Float16)v;
}

// ---- edge aggregation: MFMA edge-linear + f16 interleaved x-gather. ----
__global__ __launch_bounds__(256) void k_edgeH(
    const int* __restrict__ csrc, const int2* __restrict__ odeg,
    const _Float16* __restrict__ xg16,
    const unsigned* __restrict__ e16,
    const unsigned* __restrict__ ewmf, const float* __restrict__ ebf,
    float* __restrict__ hpre)
{
  int gt = blockIdx.x * 256 + threadIdx.x;
  int node = gt >> 6;
  if (node >= NN) return;
  int c = threadIdx.x & 63;
  int m = c & 15;    // A row (edge-in-chunk) / ch-in-group
  int qv = c >> 4;   // lane quarter

  half4_t bf[4];
  #pragma unroll
  for (int g = 0; g < 4; g++) {
    uint2 wv = *(const uint2*)(ewmf + (size_t)(g * 64 + c) * 2);
    bf[g] = __builtin_bit_cast(half4_t, wv);
  }
  float bb[4];
  #pragma unroll
  for (int g = 0; g < 4; g++) bb[g] = ebf[16 * g + m];
  int2 od = odeg[node];
  int start = od.x, n = od.y;
  float acc[4] = {0.f, 0.f, 0.f, 0.f};

  for (int base = 0; base < n; base += 16) {
    int cn = n - base;           // valid edges this chunk (may exceed 16)
    int p = start + base;
    // A fragment: coalesced 512B across the wave
    uint2 av = *(const uint2*)(e16 + (size_t)(p + m) * 8 + qv * 2);
    half4_t af = __builtin_bit_cast(half4_t, av);
    // edge linear: D[edge][ch] = A x B + bias
    f32x4 d0, d1, d2, d3;
    {
      f32x4 ci;
      ci[0] = bb[0]; ci[1] = bb[0]; ci[2] = bb[0]; ci[3] = bb[0];
      d0 = __builtin_amdgcn_mfma_f32_16x16x16f16(af, bf[0], ci, 0, 0, 0);
      ci[0] = bb[1]; ci[1] = bb[1]; ci[2] = bb[1]; ci[3] = bb[1];
      d1 = __builtin_amdgcn_mfma_f32_16x16x16f16(af, bf[1], ci, 0, 0, 0);
      ci[0] = bb[2]; ci[1] = bb[2]; ci[2] = bb[2]; ci[3] = bb[2];
      d2 = __builtin_amdgcn_mfma_f32_16x16x16f16(af, bf[2], ci, 0, 0, 0);
      ci[0] = bb[3]; ci[1] = bb[3]; ci[2] = bb[3]; ci[3] = bb[3];
      d3 = __builtin_amdgcn_mfma_f32_16x16x16f16(af, bf[3], ci, 0, 0, 0);
    }
    // src broadcast: lane holds csrc[p+m]; my 4 edges are 4*qv+r
    int sidx = csrc[p + m];
    #pragma unroll
    for (int r = 0; r < 4; r++) {
      int s = __shfl(sidx, 4 * qv + r);
      bool valid = (4 * qv + r) < cn;
      // lane's 4 channels {m,m+16,m+32,m+48} of row s: 8B contiguous
      uint2 xv = *(const uint2*)(xg16 + (size_t)s * 64 + m * 4);
      half4_t hx = __builtin_bit_cast(half4_t, xv);
      #pragma unroll
      for (int g = 0; g < 4; g++) {
        float xs = (float)hx[g];
        float el = (r == 0) ? ((g == 0) ? d0[0] : (g == 1) ? d1[0] : (g == 2) ? d2[0] : d3[0])
                 : (r == 1) ? ((g == 0) ? d0[1] : (g == 1) ? d1[1] : (g == 2) ? d2[1] : d3[1])
                 : (r == 2) ? ((g == 0) ? d0[2] : (g == 1) ? d1[2] : (g == 2) ? d2[2] : d3[2])
                 :            ((g == 0) ? d0[3] : (g == 1) ? d1[3] : (g == 2) ? d2[3] : d3[3]);
        float v = fmaxf(xs + el, 0.f);
        acc[g] += valid ? v : 0.f;
      }
    }
  }
  // reduce across lane quarters (edge split)
  #pragma unroll
  for (int g = 0; g < 4; g++) {
    acc[g] += __shfl_xor(acc[g], 16);
    acc[g] += __shfl_xor(acc[g], 32);
  }
  float xself = (float)xg16[(size_t)node * 64 + (c & 15) * 4 + (c >> 4)];
  float sum = (qv == 0) ? acc[0] : (qv == 1) ? acc[1] : (qv == 2) ? acc[2] : acc[3];
  hpre[(size_t)node * 64 + c] = xself + sum;
}

// ---- node MLP v5: MFMA. Block = 256 = 4 waves over 64 rows; wave = col-group.
//      Stage A: hpre (f32, global, coalesced dwordx4) -> f16 in-reg -> 4 chained
//      mfma per 16x16 tile (K=64); relu -> f16 mid tile in LDS. Stage B: mid
//      A-frags from LDS (b64) x w2 B-frags -> out; relu, h2 store, BN stats.
//      Fragment mappings identical to the harness-verified edge MFMA. ----
__global__ __launch_bounds__(256) void k_mlp(
    const float* __restrict__ hpre,
    const unsigned* __restrict__ wBL,   // [mat][kb][cg][lane][2] dwords
    const float* __restrict__ b1f, const float* __restrict__ b2v,
    float* __restrict__ h2, float* __restrict__ bnsq)
{
  __shared__ _Float16 ml[64 * 72];   // mid tile, stride 72 f16
  int tid = threadIdx.x;
  int cg = __builtin_amdgcn_readfirstlane(tid >> 6);   // wave = col group
  int l = tid & 63;
  int m = l & 15;    // col within group / row within row-group
  int q = l >> 4;    // lane quarter
  int rbase = blockIdx.x * 64;
  int col = cg * 16 + m;

  uint2 w1f[4], w2f[4];
  #pragma unroll
  for (int kb = 0; kb < 4; kb++) {
    w1f[kb] = *(const uint2*)(wBL + (size_t)(((0 * 4 + kb) * 4 + cg) * 64 + l) * 2);
    w2f[kb] = *(const uint2*)(wBL + (size_t)(((1 * 4 + kb) * 4 + cg) * 64 + l) * 2);
  }
  float b1c = b1f[col], b2c = b2v[col];

  // stage A: mid = relu(hpre @ w1^T + b1) -> ml (f16)
  #pragma unroll
  for (int rg = 0; rg < 4; rg++) {
    int row = rbase + rg * 16 + m;
    const float* hp = hpre + (size_t)(row < NN ? row : (NN - 1)) * 64 + 4 * q;
    f32x4 hv0 = *(const f32x4*)(hp + 0);
    f32x4 hv1 = *(const f32x4*)(hp + 16);
    f32x4 hv2 = *(const f32x4*)(hp + 32);
    f32x4 hv3 = *(const f32x4*)(hp + 48);
    f32x4 acc; acc[0] = b1c; acc[1] = b1c; acc[2] = b1c; acc[3] = b1c;
    half4_t a0, a1, a2, a3;
    #pragma unroll
    for (int i = 0; i < 4; i++) {
      a0[i] = (_Float16)hv0[i]; a1[i] = (_Float16)hv1[i];
      a2[i] = (_Float16)hv2[i]; a3[i] = (_Float16)hv3[i];
    }
    acc = __builtin_amdgcn_mfma_f32_16x16x16f16(a0, __builtin_bit_cast(half4_t, w1f[0]), acc, 0, 0, 0);
    acc = __builtin_amdgcn_mfma_f32_16x16x16f16(a1, __builtin_bit_cast(half4_t, w1f[1]), acc, 0, 0, 0);
    acc = __builtin_amdgcn_mfma_f32_16x16x16f16(a2, __builtin_bit_cast(half4_t, w1f[2]), acc, 0, 0, 0);
    acc = __builtin_amdgcn_mfma_f32_16x16x16f16(a3, __builtin_bit_cast(half4_t, w1f[3]), acc, 0, 0, 0);
    // D: lane holds rows rg*16 + q*4 + i, column 'col'
    #pragma unroll
    for (int i = 0; i < 4; i++)
      ml[(rg * 16 + q * 4 + i) * 72 + col] = (_Float16)fmaxf(acc[i], 0.f);
  }
  __syncthreads();
  // stage B: out = relu(mid @ w2^T + b2)
  float sacc = 0.f, qacc = 0.f;
  #pragma unroll
  for (int rg = 0; rg < 4; rg++) {
    f32x4 acc; acc[0] = b2c; acc[1] = b2c; acc[2] = b2c; acc[3] = b2c;
    #pragma unroll
    for (int kb = 0; kb < 4; kb++) {
      half4_t a = *(const half4_t*)(ml + (rg * 16 + m) * 72 + kb * 16 + 4 * q);
      acc = __builtin_amdgcn_mfma_f32_16x16x16f16(a, __builtin_bit_cast(half4_t, w2f[kb]), acc, 0, 0, 0);
    }
    #pragma unroll
    for (int i = 0; i < 4; i++) {
      int row = rbase + rg * 16 + q * 4 + i;
      bool rok = row < NN;
      float v = rok ? fmaxf(acc[i], 0.f) : 0.f;
      if (rok) h2[(size_t)row * 64 + col] = v;
      sacc += v; qacc += v * v;
    }
  }
  // reduce across row-quarters -> per-col totals (all lanes of same m hold total)
  sacc += __shfl_xor(sacc, 16); sacc += __shfl_xor(sacc, 32);
  qacc += __shfl_xor(qacc, 16); qacc += __shfl_xor(qacc, 32);
  int cp = (blockIdx.x & 31) * 128;
  if (q == 0) {
    atomicAdd(&bnsq[cp + col], sacc);
    atomicAdd(&bnsq[cp + 64 + col], qacc);
  }
}

__global__ __launch_bounds__(64) void k_bnfin(const float* __restrict__ bnsq,
                                              const float* __restrict__ gamma, const float* __restrict__ beta,
                                              int layer, float* __restrict__ scs, float* __restrict__ shs) {
  int c = threadIdx.x;
  if (c >= 64) return;
  const float* sl = bnsq + (size_t)layer * 4096;
  float s = 0.f, q = 0.f;
  for (int cp = 0; cp < 32; cp++) { s += sl[cp * 128 + c]; q += sl[cp * 128 + 64 + c]; }
  float mu = s * (1.0f / NN);
  float var = q * (1.0f / NN) - mu * mu;
  float r = rsqrtf(var + 1e-5f);
  float g = gamma[layer * 64 + c] * r;
  scs[layer * 64 + c] = g;
  shs[layer * 64 + c] = beta[layer * 64 + c] - mu * g;
}

// ---- pool: BN+relu on the fly; batch sorted -> contiguous ranges ----
__global__ __launch_bounds__(256) void k_pool2(const float* __restrict__ h2, const float* __restrict__ sc,
                                               const float* __restrict__ sh, const int* __restrict__ gstart,
                                               float* __restrict__ pooled) {
  int g = blockIdx.x >> 2, sub = blockIdx.x & 3;
  int s = gstart[g], e = gstart[g + 1];
  int c = threadIdx.x & 63, rg = threadIdx.x >> 6;
  float scv = sc[c], shv = sh[c];
  float acc = 0.f;
  for (int r = s + sub * 4 + rg; r < e; r += 16)
    acc += fmaxf(fmaf(h2[(size_t)r * 64 + c], scv, shv), 0.f);
  __shared__ float ls[256];
  ls[threadIdx.x] = acc;
  __syncthreads();
  if (rg == 0) {
    float v = ls[c] + ls[64 + c] + ls[128 + c] + ls[192 + c];
    atomicAdd(&pooled[g * 64 + c], v);
  }
}

__global__ __launch_bounds__(128) void k_head(const float* __restrict__ pooled, const int* __restrict__ gstart,
                                              const float* __restrict__ hw1, const float* __restrict__ hb1,
                                              const float* __restrict__ hw2, const float* __restrict__ hb2,
                                              float* __restrict__ out) {
  __shared__ float p[64];
  __shared__ float z[128];
  int g = blockIdx.x, t = threadIdx.x;
  if (t < 64) {
    int cn = gstart[g + 1] - gstart[g];
    float inv = 1.0f / (float)(cn > 0 ? cn : 1);
    p[t] = pooled[g * 64 + t] * inv;
  }
  __syncthreads();
  float a = hb1[t];
  #pragma unroll
  for (int k = 0; k < 64; k++) a = fmaf(hw1[t * 64 + k], p[k], a);
  z[t] = fmaxf(a, 0.f);
  __syncthreads();
  if (t < OUTC) {
    float b = hb2[t];
    #pragma unroll
    for (int k = 0; k < 128; k++) b = fmaf(hw2[t * 128 + k], z[k], b);
    out[g * OUTC + t] = b;
  }
}

extern "C" void kernel_launch(void* const* d_in, const int* in_sizes, int n_in,
                              void* d_out, int out_size, void* d_ws, size_t ws_size,
                              hipStream_t stream) {
  const float* x_f   = (const float*)d_in[0];
  const int*   ei    = (const int*)d_in[1];
  const float* eattr = (const float*)d_in[2];
  const int*   batch = (const int*)d_in[3];
  const float* l0_ew = (const float*)d_in[4];
  const float* l0_eb = (const float*)d_in[5];
  const float* l0_w1 = (const float*)d_in[6];
  const float* l0_b1 = (const float*)d_in[7];
  const float* l0_w2 = (const float*)d_in[8];
  const float* l0_b2 = (const float*)d_in[9];
  const float* ew    = (const float*)d_in[10];
  const float* eb    = (const float*)d_in[11];
  const float* w1    = (const float*)d_in[12];
  const float* b1    = (const float*)d_in[13];
  const float* w2    = (const float*)d_in[14];
  const float* b2    = (const float*)d_in[15];
  const float* bng   = (const float*)d_in[16];
  const float* bnb   = (const float*)d_in[17];
  const float* hw1   = (const float*)d_in[18];
  const float* hb1   = (const float*)d_in[19];
  const float* hw2   = (const float*)d_in[20];
  const float* hb2   = (const float*)d_in[21];
  const int* esrc = ei;
  const int* edst = ei + NE;

  char* wsb = (char*)d_ws;
  size_t off = 0;
  auto A = [&](size_t bytes) -> void* {
    void* p = wsb + off;
    off = (off + bytes + 255) & ~(size_t)255;
    return p;
  };
  int*   csrc = (int*)A((size_t)(NE + 16) * 4);
  int*   offs = (int*)A((size_t)NN * 4);
  int*   deg  = (int*)A((size_t)NN * 4);
  int*   cur  = (int*)A((size_t)NN * 4);
  int2*  odeg = (int2*)A((size_t)NN * 8);
  int*   bsum = (int*)A(128 * 4);
  int*   gst  = (int*)A((NG + 1) * 4);
  _Float16* xg16 = (_Float16*)A((size_t)NN * 64 * 2);  // f16 interleaved gather operand
  float* hpre = (float*)A((size_t)NN * 64 * 4);
  float* h2   = (float*)A((size_t)NN * 64 * 4);
  float* bnsq = (float*)A(4 * 32 * 128 * 4);   // [layer][copy0..31][sum64|sq64]
  float* scs  = (float*)A(4 * 64 * 4);
  float* shs  = (float*)A(4 * 64 * 4);
  float* pooled = (float*)A((size_t)NG * 64 * 4);
  unsigned* wB   = (unsigned*)A(16384 * 4);  // MFMA B-frag node-MLP weights, 4 layers x 2 mats
  unsigned* ewmf = (unsigned*)A(2048 * 4);   // MFMA-layout f16 edge weights, 4 layers
  float* ebp  = (float*)A(256 * 4);          // padded edge biases, 4 layers
  unsigned* e16 = (unsigned*)A(((size_t)NE + 16) * 32);  // f16 eattr, CSR order, 8 dwords/edge

  hipMemsetAsync(deg, 0, (size_t)NN * 4, stream);
  hipMemsetAsync(bnsq, 0, 4 * 32 * 128 * 4, stream);
  hipMemsetAsync(pooled, 0, (size_t)NG * 64 * 4, stream);
  hipMemsetAsync(csrc + NE, 0, 16 * 4, stream);            // pad: safe src idx for tail chunks
  hipMemsetAsync((char*)e16 + (size_t)NE * 32, 0, 16 * 32, stream);  // pad: clean A-frag tail

  k_wmlp<<<64, 256, 0, stream>>>(l0_w1, w1, l0_w2, w2, wB);
  k_wprep<<<8, 256, 0, stream>>>(l0_ew, l0_eb, ew, eb, ewmf, ebp);
  k_xpad16<<<(NN * 64 + 255) / 256, 256, 0, stream>>>(x_f, xg16);
  k_gstart<<<(NN + 255) / 256, 256, 0, stream>>>(batch, gst);

  k_deg<<<(NE + 255) / 256, 256, 0, stream>>>(edst, deg);
  k_scan1<<<98, 1024, 0, stream>>>(deg, offs, bsum);
  k_scan2<<<1, 128, 0, stream>>>(bsum, 98);
  k_scan3<<<(NN + 255) / 256, 256, 0, stream>>>(offs, bsum, deg, cur, odeg);
  k_fillcast<<<(NE + 255) / 256, 256, 0, stream>>>(esrc, edst, cur, (const float4*)eattr,
                                                   csrc, (uint4*)e16);

  const int nodeBlocks = (NN * 64 + 255) / 256;
  const int rowBlocks = (NN + 63) / 64;
  const int elemBlocks = (NN * 64 + 255) / 256;

  // ---- layer 0 (padded to C=64) ----
  k_edgeH<<<nodeBlocks, 256, 0, stream>>>(csrc, odeg, xg16, e16, ewmf, ebp, hpre);
  k_mlp<<<rowBlocks, 256, 0, stream>>>(hpre, wB, l0_b1, l0_b2, h2, bnsq + 0);
  k_bnfin<<<1, 64, 0, stream>>>(bnsq, bng, bnb, 0, scs, shs);

  // ---- layers 1..3: pre-apply BN(prev)+relu -> f16 gather operand ----
  for (int i = 0; i < 3; i++) {
    k_bnapply<<<elemBlocks, 256, 0, stream>>>(h2, scs + i * 64, shs + i * 64, xg16);
    k_edgeH<<<nodeBlocks, 256, 0, stream>>>(csrc, odeg, xg16,
                                            e16, ewmf + (size_t)(i + 1) * 512, ebp + (i + 1) * 64, hpre);
    k_mlp<<<rowBlocks, 256, 0, stream>>>(hpre, wB + (size_t)(i + 1) * 4096, b1 + (size_t)i * 64,
                                         b2 + (size_t)i * 64, h2, bnsq + (size_t)(i + 1) * 4096);
    k_bnfin<<<1, 64, 0, stream>>>(bnsq, bng, bnb, i + 1, scs, shs);
  }

  // ---- pool (applies BN layer 3) + head ----
  k_pool2<<<NG * 4, 256, 0, stream>>>(h2, scs + 3 * 64, shs + 3 * 64, gst, pooled);
  k_head<<<NG, 128, 0, stream>>>(pooled, gst, hw1, hb1, hw2, hb2, (float*)d_out);
}

// Round 8
// 731.090 us; speedup vs baseline: 4.7682x; 1.1420x over previous
//
#include <hip/hip_runtime.h>
#include <hip/hip_fp16.h>

// Problem constants
#define NN 100000
#define NE 1600000
#define DIN 32
#define DE 16
#define HC 64
#define NL 4
#define MHC 128
#define OUTC 10
#define NG 128

typedef _Float16 half4_t __attribute__((ext_vector_type(4)));
typedef float f32x4 __attribute__((ext_vector_type(4)));

// ---- CSR build ----
__global__ __launch_bounds__(256) void k_deg(const int* __restrict__ dst, int* __restrict__ deg) {
  int e = blockIdx.x * 256 + threadIdx.x;
  if (e < NE) atomicAdd(&deg[dst[e]], 1);
}

__global__ __launch_bounds__(1024) void k_scan1(const int* __restrict__ deg, int* __restrict__ offs, int* __restrict__ bsum) {
  __shared__ int s[1024];
  int t = threadIdx.x;
  int i = blockIdx.x * 1024 + t;
  int v = (i < NN) ? deg[i] : 0;
  s[t] = v; __syncthreads();
  for (int d = 1; d < 1024; d <<= 1) {
    int x = 0;
    if (t >= d) x = s[t - d];
    __syncthreads();
    if (t >= d) s[t] += x;
    __syncthreads();
  }
  if (i < NN) offs[i] = s[t] - v;
  if (t == 1023) bsum[blockIdx.x] = s[t];
}

__global__ __launch_bounds__(128) void k_scan2(int* __restrict__ bsum, int nb) {
  __shared__ int s[128];
  int t = threadIdx.x;
  int v = (t < nb) ? bsum[t] : 0;
  s[t] = v; __syncthreads();
  for (int d = 1; d < 128; d <<= 1) {
    int x = 0;
    if (t >= d) x = s[t - d];
    __syncthreads();
    if (t >= d) s[t] += x;
    __syncthreads();
  }
  if (t < nb) bsum[t] = s[t] - v;
}

// also builds odeg = (start, deg) int2
__global__ __launch_bounds__(256) void k_scan3(int* __restrict__ offs, const int* __restrict__ bsum,
                                               const int* __restrict__ deg,
                                               int* __restrict__ cur, int2* __restrict__ odeg) {
  int i = blockIdx.x * 256 + threadIdx.x;
  if (i < NN) {
    int o = offs[i] + bsum[i >> 10];
    offs[i] = o;
    cur[i] = o;
    odeg[i] = make_int2(o, deg[i]);
  }
}

// ---- fused fill + cast: one pass over edges (coalesced reads of src/dst/eattr),
//      scatter-write csrc (4B) + e16 (32B, single 64B line) at CSR position. ----
__global__ __launch_bounds__(256) void k_fillcast(const int* __restrict__ src, const int* __restrict__ dst,
                                                  int* __restrict__ cur,
                                                  const float4* __restrict__ eattr4,
                                                  int* __restrict__ csrc, uint4* __restrict__ e16) {
  int e = blockIdx.x * 256 + threadIdx.x;
  if (e >= NE) return;
  int d = dst[e];
  float4 a0 = eattr4[(size_t)e * 4 + 0];
  float4 a1 = eattr4[(size_t)e * 4 + 1];
  float4 a2 = eattr4[(size_t)e * 4 + 2];
  float4 a3 = eattr4[(size_t)e * 4 + 3];
  int s = src[e];
  int pos = atomicAdd(&cur[d], 1);
  __half2 h0 = __floats2half2_rn(a0.x, a0.y), h1 = __floats2half2_rn(a0.z, a0.w);
  __half2 h2 = __floats2half2_rn(a1.x, a1.y), h3 = __floats2half2_rn(a1.z, a1.w);
  __half2 h4 = __floats2half2_rn(a2.x, a2.y), h5 = __floats2half2_rn(a2.z, a2.w);
  __half2 h6 = __floats2half2_rn(a3.x, a3.y), h7 = __floats2half2_rn(a3.z, a3.w);
  uint4 o0 = make_uint4(*(unsigned*)&h0, *(unsigned*)&h1, *(unsigned*)&h2, *(unsigned*)&h3);
  uint4 o1 = make_uint4(*(unsigned*)&h4, *(unsigned*)&h5, *(unsigned*)&h6, *(unsigned*)&h7);
  csrc[pos] = s;
  e16[(size_t)pos * 2 + 0] = o0;
  e16[(size_t)pos * 2 + 1] = o1;
}

// ---- edge weights -> MFMA B-fragment layout [4 layers][4 grp][64 lane][2 dw]
//      + padded biases [4][64] ----
__global__ __launch_bounds__(256) void k_wprep(const float* __restrict__ l0ew, const float* __restrict__ l0eb,
                                               const float* __restrict__ ew, const float* __restrict__ eb,
                                               unsigned* __restrict__ ewmf, float* __restrict__ ebp) {
  int i = blockIdx.x * 256 + threadIdx.x;
  if (i < 2048) {
    int j = i & 1;           // dword within lane fragment
    int l = (i >> 1) & 63;   // lane
    int g = (i >> 7) & 3;    // channel group
    int L = i >> 9;          // layer
    int ch = 16 * g + (l & 15);
    int k0 = 4 * (l >> 4) + 2 * j;
    float a, b;
    if (L == 0) {
      a = (ch < 32) ? l0ew[ch * 16 + k0] : 0.f;
      b = (ch < 32) ? l0ew[ch * 16 + k0 + 1] : 0.f;
    } else {
      a = ew[(size_t)(L - 1) * 1024 + ch * 16 + k0];
      b = ew[(size_t)(L - 1) * 1024 + ch * 16 + k0 + 1];
    }
    __half2 h = __floats2half2_rn(a, b);
    ewmf[i] = *(unsigned*)&h;
  }
  if (i < 256) {
    int L = i >> 6, c = i & 63;
    ebp[i] = (L == 0) ? ((c < 32) ? l0eb[c] : 0.f) : eb[(size_t)(L - 1) * 64 + c];
  }
}

// ---- node-MLP weights -> MFMA B-fragments, f16.
//      wB[L][mat][kb][cg][lane][j]: value pair = W[c][k0], W[c][k0+1]
//      with c = cg*16+(lane&15), k0 = kb*16 + 4*(lane>>4) + 2*j.
//      mat0 = w1 (layer0: [64][32], k>=32 zero), mat1 = w2 ([64][64]). ----
__global__ __launch_bounds__(256) void k_wmlp(const float* __restrict__ l0w1, const float* __restrict__ w1,
                                              const float* __restrict__ l0w2, const float* __restrict__ w2,
                                              unsigned* __restrict__ wB) {
  int id = blockIdx.x * 256 + threadIdx.x;
  if (id >= 16384) return;
  int j = id & 1;
  int l = (id >> 1) & 63;
  int cg = (id >> 7) & 3;
  int kb = (id >> 9) & 3;
  int mat = (id >> 11) & 1;
  int L = (id >> 12) & 3;
  int k0 = kb * 16 + 4 * (l >> 4) + 2 * j;
  int c = cg * 16 + (l & 15);
  float a, b;
  if (mat == 0) {
    if (L == 0) {
      a = (k0 < 32) ? l0w1[c * 32 + k0] : 0.f;
      b = (k0 + 1 < 32) ? l0w1[c * 32 + k0 + 1] : 0.f;
    } else {
      a = w1[(size_t)(L - 1) * 4096 + c * 64 + k0];
      b = w1[(size_t)(L - 1) * 4096 + c * 64 + k0 + 1];
    }
  } else {
    if (L == 0) {
      a = l0w2[c * 64 + k0];
      b = l0w2[c * 64 + k0 + 1];
    } else {
      a = w2[(size_t)(L - 1) * 4096 + c * 64 + k0];
      b = w2[(size_t)(L - 1) * 4096 + c * 64 + k0 + 1];
    }
  }
  __half2 h = __floats2half2_rn(a, b);
  wB[id] = *(unsigned*)&h;
}

// ---- graph boundaries (batch sorted) ----
__global__ __launch_bounds__(256) void k_gstart(const int* __restrict__ batch, int* __restrict__ gstart) {
  int i = blockIdx.x * 256 + threadIdx.x;
  if (i >= NN) return;
  int b = batch[i];
  int bp = (i == 0) ? -1 : batch[i - 1];
  for (int g = bp + 1; g <= b; g++) gstart[g] = i;
  if (i == NN - 1)
    for (int g = b + 1; g <= NG; g++) gstart[g] = NN;
}

// ---- x -> f16 channel-interleaved gather layout xg16[row][(c&15)*4 + (c>>4)],
//      ch>=32 zero (layer-0 padding). ----
__global__ __launch_bounds__(256) void k_xpad16(const float* __restrict__ x, _Float16* __restrict__ xg16) {
  int i = blockIdx.x * 256 + threadIdx.x;   // over NN*64
  if (i >= NN * 64) return;
  int row = i >> 6, c = i & 63;
  float v = (c < 32) ? x[(size_t)row * 32 + c] : 0.f;
  xg16[(size_t)row * 64 + (c & 15) * 4 + (c >> 4)] = (_Float16)v;
}

// ---- BN+relu applied once per layer: h2 (f32) -> xg16 (f16, interleaved). ----
__global__ __launch_bounds__(256) void k_bnapply(const float* __restrict__ h2,
                                                 const float* __restrict__ sc, const float* __restrict__ sh,
                                                 _Float16* __restrict__ xg16) {
  int i = blockIdx.x * 256 + threadIdx.x;   // over NN*64
  if (i >= NN * 64) return;
  int row = i >> 6, c = i & 63;
  float v = fmaxf(fmaf(h2[i], sc[c], sh[c]), 0.f);
  xg16[(size_t)row * 64 + (c & 15) * 4 + (c >> 4)] = (_Float16)v;
}

// ---- fused layer: edge aggregation (MFMA edge-linear, wave-per-node over 16
//      nodes/wave) -> LDS tile -> node MLP (MFMA) -> h2 + BN stats.
//      R7 lesson: edgeH and mlp were separate with a 51 MB/layer hpre round
//      trip; block = 64 nodes fuses them. Phase 1 per-wave work = sum of 16
//      degrees (better balance than 1 node/wave). Fragment mappings identical
//      to the harness-verified R7 kernels; hl stays f32 (no new quantization). ----
__global__ __launch_bounds__(256) void k_layer(
    const int* __restrict__ csrc, const int2* __restrict__ odeg,
    const _Float16* __restrict__ xg16,
    const unsigned* __restrict__ e16,
    const unsigned* __restrict__ ewmf, const float* __restrict__ ebf,
    const unsigned* __restrict__ wBL,   // [mat][kb][cg][lane][2] dwords
    const float* __restrict__ b1f, const float* __restrict__ b2v,
    float* __restrict__ h2, float* __restrict__ bnsq)
{
  __shared__ float hl[64 * 68];      // aggregated node features (f32), stride 68
  __shared__ _Float16 ml[64 * 72];   // mid activations (f16), stride 72
  int tid = threadIdx.x;
  int cg = __builtin_amdgcn_readfirstlane(tid >> 6);   // wave id = col group
  int l = tid & 63;
  int m = l & 15;    // A row / col-in-group
  int q = l >> 4;    // lane quarter
  int rbase = blockIdx.x * 64;
  int col = cg * 16 + m;

  // edge-linear B fragments + bias
  half4_t bf[4];
  #pragma unroll
  for (int g = 0; g < 4; g++) {
    uint2 wv = *(const uint2*)(ewmf + (size_t)(g * 64 + l) * 2);
    bf[g] = __builtin_bit_cast(half4_t, wv);
  }
  float bb[4];
  #pragma unroll
  for (int g = 0; g < 4; g++) bb[g] = ebf[16 * g + m];
  // node-MLP B fragments + biases (issued early; live through phase 1)
  uint2 w1f[4], w2f[4];
  #pragma unroll
  for (int kb = 0; kb < 4; kb++) {
    w1f[kb] = *(const uint2*)(wBL + (size_t)(((0 * 4 + kb) * 4 + cg) * 64 + l) * 2);
    w2f[kb] = *(const uint2*)(wBL + (size_t)(((1 * 4 + kb) * 4 + cg) * 64 + l) * 2);
  }
  float b1c = b1f[col], b2c = b2v[col];

  // ---- phase 1: edge aggregation, 16 nodes per wave ----
  for (int t = 0; t < 16; t++) {
    int node = rbase + cg * 16 + t;
    float hv = 0.f;
    if (node < NN) {
      int2 od = odeg[node];
      int start = od.x, n = od.y;
      float acc[4] = {0.f, 0.f, 0.f, 0.f};
      for (int base = 0; base < n; base += 16) {
        int cn = n - base;
        int p = start + base;
        uint2 av = *(const uint2*)(e16 + (size_t)(p + m) * 8 + q * 2);
        half4_t af = __builtin_bit_cast(half4_t, av);
        f32x4 d0, d1, d2, d3;
        {
          f32x4 ci;
          ci[0] = bb[0]; ci[1] = bb[0]; ci[2] = bb[0]; ci[3] = bb[0];
          d0 = __builtin_amdgcn_mfma_f32_16x16x16f16(af, bf[0], ci, 0, 0, 0);
          ci[0] = bb[1]; ci[1] = bb[1]; ci[2] = bb[1]; ci[3] = bb[1];
          d1 = __builtin_amdgcn_mfma_f32_16x16x16f16(af, bf[1], ci, 0, 0, 0);
          ci[0] = bb[2]; ci[1] = bb[2]; ci[2] = bb[2]; ci[3] = bb[2];
          d2 = __builtin_amdgcn_mfma_f32_16x16x16f16(af, bf[2], ci, 0, 0, 0);
          ci[0] = bb[3]; ci[1] = bb[3]; ci[2] = bb[3]; ci[3] = bb[3];
          d3 = __builtin_amdgcn_mfma_f32_16x16x16f16(af, bf[3], ci, 0, 0, 0);
        }
        int sidx = csrc[p + m];
        #pragma unroll
        for (int r = 0; r < 4; r++) {
          int s = __shfl(sidx, 4 * q + r);
          bool valid = (4 * q + r) < cn;
          uint2 xv = *(const uint2*)(xg16 + (size_t)s * 64 + m * 4);
          half4_t hx = __builtin_bit_cast(half4_t, xv);
          #pragma unroll
          for (int g = 0; g < 4; g++) {
            float xs = (float)hx[g];
            float el = (r == 0) ? ((g == 0) ? d0[0] : (g == 1) ? d1[0] : (g == 2) ? d2[0] : d3[0])
                     : (r == 1) ? ((g == 0) ? d0[1] : (g == 1) ? d1[1] : (g == 2) ? d2[1] : d3[1])
                     : (r == 2) ? ((g == 0) ? d0[2] : (g == 1) ? d1[2] : (g == 2) ? d2[2] : d3[2])
                     :            ((g == 0) ? d0[3] : (g == 1) ? d1[3] : (g == 2) ? d2[3] : d3[3]);
            float v = fmaxf(xs + el, 0.f);
            acc[g] += valid ? v : 0.f;
          }
        }
      }
      #pragma unroll
      for (int g = 0; g < 4; g++) {
        acc[g] += __shfl_xor(acc[g], 16);
        acc[g] += __shfl_xor(acc[g], 32);
      }
      float xself = (float)xg16[(size_t)node * 64 + (l & 15) * 4 + (l >> 4)];
      float sum = (q == 0) ? acc[0] : (q == 1) ? acc[1] : (q == 2) ? acc[2] : acc[3];
      hv = xself + sum;
    }
    hl[(cg * 16 + t) * 68 + l] = hv;   // lane l = channel l
  }
  __syncthreads();

  // ---- phase 2 stage A: mid = relu(hl @ w1^T + b1) -> ml (f16) ----
  #pragma unroll
  for (int rg = 0; rg < 4; rg++) {
    const float* hp = hl + (rg * 16 + m) * 68 + 4 * q;
    f32x4 hv0 = *(const f32x4*)(hp + 0);
    f32x4 hv1 = *(const f32x4*)(hp + 16);
    f32x4 hv2 = *(const f32x4*)(hp + 32);
    f32x4 hv3 = *(const f32x4*)(hp + 48);
    f32x4 acc; acc[0] = b1c; acc[1] = b1c; acc[2] = b1c; acc[3] = b1c;
    half4_t a0, a1, a2, a3;
    #pragma unroll
    for (int i = 0; i < 4; i++) {
      a0[i] = (_Float16)hv0[i]; a1[i] = (_Float16)hv1[i];
      a2[i] = (_Float16)hv2[i]; a3[i] = (_Float16)hv3[i];
    }
    acc = __builtin_amdgcn_mfma_f32_16x16x16f16(a0, __builtin_bit_cast(half4_t, w1f[0]), acc, 0, 0, 0);
    acc = __builtin_amdgcn_mfma_f32_16x16x16f16(a1, __builtin_bit_cast(half4_t, w1f[1]), acc, 0, 0, 0);
    acc = __builtin_amdgcn_mfma_f32_16x16x16f16(a2, __builtin_bit_cast(half4_t, w1f[2]), acc, 0, 0, 0);
    acc = __builtin_amdgcn_mfma_f32_16x16x16f16(a3, __builtin_bit_cast(half4_t, w1f[3]), acc, 0, 0, 0);
    #pragma unroll
    for (int i = 0; i < 4; i++)
      ml[(rg * 16 + q * 4 + i) * 72 + col] = (_Float16)fmaxf(acc[i], 0.f);
  }
  __syncthreads();

  // ---- phase 2 stage B: out = relu(mid @ w2^T + b2); h2 store + BN stats ----
  float sacc = 0.f, qacc = 0.f;
  #pragma unroll
  for (int rg = 0; rg < 4; rg++) {
    f32x4 acc; acc[0] = b2c; acc[1] = b2c; acc[2] = b2c; acc[3] = b2c;
    #pragma unroll
    for (int kb = 0; kb < 4; kb++) {
      half4_t a = *(const half4_t*)(ml + (rg * 16 + m) * 72 + kb * 16 + 4 * q);
      acc = __builtin_amdgcn_mfma_f32_16x16x16f16(a, __builtin_bit_cast(half4_t, w2f[kb]), acc, 0, 0, 0);
    }
    #pragma unroll
    for (int i = 0; i < 4; i++) {
      int row = rbase + rg * 16 + q * 4 + i;
      bool rok = row < NN;
      float v = rok ? fmaxf(acc[i], 0.f) : 0.f;
      if (rok) h2[(size_t)row * 64 + col] = v;
      sacc += v; qacc += v * v;
    }
  }
  sacc += __shfl_xor(sacc, 16); sacc += __shfl_xor(sacc, 32);
  qacc += __shfl_xor(qacc, 16); qacc += __shfl_xor(qacc, 32);
  int cp = (blockIdx.x & 31) * 128;
  if (q == 0) {
    atomicAdd(&bnsq[cp + col], sacc);
    atomicAdd(&bnsq[cp + 64 + col], qacc);
  }
}

__global__ __launch_bounds__(64) void k_bnfin(const float* __restrict__ bnsq,
                                              const float* __restrict__ gamma, const float* __restrict__ beta,
                                              int layer, float* __restrict__ scs, float* __restrict__ shs) {
  int c = threadIdx.x;
  if (c >= 64) return;
  const float* sl = bnsq + (size_t)layer * 4096;
  float s = 0.f, q = 0.f;
  for (int cp = 0; cp < 32; cp++) { s += sl[cp * 128 + c]; q += sl[cp * 128 + 64 + c]; }
  float mu = s * (1.0f / NN);
  float var = q * (1.0f / NN) - mu * mu;
  float r = rsqrtf(var + 1e-5f);
  float g = gamma[layer * 64 + c] * r;
  scs[layer * 64 + c] = g;
  shs[layer * 64 + c] = beta[layer * 64 + c] - mu * g;
}

// ---- pool: BN+relu on the fly; batch sorted -> contiguous ranges ----
__global__ __launch_bounds__(256) void k_pool2(const float* __restrict__ h2, const float* __restrict__ sc,
                                               const float* __restrict__ sh, const int* __restrict__ gstart,
                                               float* __restrict__ pooled) {
  int g = blockIdx.x >> 2, sub = blockIdx.x & 3;
  int s = gstart[g], e = gstart[g + 1];
  int c = threadIdx.x & 63, rg = threadIdx.x >> 6;
  float scv = sc[c], shv = sh[c];
  float acc = 0.f;
  for (int r = s + sub * 4 + rg; r < e; r += 16)
    acc += fmaxf(fmaf(h2[(size_t)r * 64 + c], scv, shv), 0.f);
  __shared__ float ls[256];
  ls[threadIdx.x] = acc;
  __syncthreads();
  if (rg == 0) {
    float v = ls[c] + ls[64 + c] + ls[128 + c] + ls[192 + c];
    atomicAdd(&pooled[g * 64 + c], v);
  }
}

__global__ __launch_bounds__(128) void k_head(const float* __restrict__ pooled, const int* __restrict__ gstart,
                                              const float* __restrict__ hw1, const float* __restrict__ hb1,
                                              const float* __restrict__ hw2, const float* __restrict__ hb2,
                                              float* __restrict__ out) {
  __shared__ float p[64];
  __shared__ float z[128];
  int g = blockIdx.x, t = threadIdx.x;
  if (t < 64) {
    int cn = gstart[g + 1] - gstart[g];
    float inv = 1.0f / (float)(cn > 0 ? cn : 1);
    p[t] = pooled[g * 64 + t] * inv;
  }
  __syncthreads();
  float a = hb1[t];
  #pragma unroll
  for (int k = 0; k < 64; k++) a = fmaf(hw1[t * 64 + k], p[k], a);
  z[t] = fmaxf(a, 0.f);
  __syncthreads();
  if (t < OUTC) {
    float b = hb2[t];
    #pragma unroll
    for (int k = 0; k < 128; k++) b = fmaf(hw2[t * 128 + k], z[k], b);
    out[g * OUTC + t] = b;
  }
}

extern "C" void kernel_launch(void* const* d_in, const int* in_sizes, int n_in,
                              void* d_out, int out_size, void* d_ws, size_t ws_size,
                              hipStream_t stream) {
  const float* x_f   = (const float*)d_in[0];
  const int*   ei    = (const int*)d_in[1];
  const float* eattr = (const float*)d_in[2];
  const int*   batch = (const int*)d_in[3];
  const float* l0_ew = (const float*)d_in[4];
  const float* l0_eb = (const float*)d_in[5];
  const float* l0_w1 = (const float*)d_in[6];
  const float* l0_b1 = (const float*)d_in[7];
  const float* l0_w2 = (const float*)d_in[8];
  const float* l0_b2 = (const float*)d_in[9];
  const float* ew    = (const float*)d_in[10];
  const float* eb    = (const float*)d_in[11];
  const float* w1    = (const float*)d_in[12];
  const float* b1    = (const float*)d_in[13];
  const float* w2    = (const float*)d_in[14];
  const float* b2    = (const float*)d_in[15];
  const float* bng   = (const float*)d_in[16];
  const float* bnb   = (const float*)d_in[17];
  const float* hw1   = (const float*)d_in[18];
  const float* hb1   = (const float*)d_in[19];
  const float* hw2   = (const float*)d_in[20];
  const float* hb2   = (const float*)d_in[21];
  const int* esrc = ei;
  const int* edst = ei + NE;

  char* wsb = (char*)d_ws;
  size_t off = 0;
  auto A = [&](size_t bytes) -> void* {
    void* p = wsb + off;
    off = (off + bytes + 255) & ~(size_t)255;
    return p;
  };
  int*   csrc = (int*)A((size_t)(NE + 16) * 4);
  int*   offs = (int*)A((size_t)NN * 4);
  int*   deg  = (int*)A((size_t)NN * 4);
  int*   cur  = (int*)A((size_t)NN * 4);
  int2*  odeg = (int2*)A((size_t)NN * 8);
  int*   bsum = (int*)A(128 * 4);
  int*   gst  = (int*)A((NG + 1) * 4);
  _Float16* xg16 = (_Float16*)A((size_t)NN * 64 * 2);  // f16 interleaved gather operand
  float* h2   = (float*)A((size_t)NN * 64 * 4);
  float* bnsq = (float*)A(4 * 32 * 128 * 4);   // [layer][copy0..31][sum64|sq64]
  float* scs  = (float*)A(4 * 64 * 4);
  float* shs  = (float*)A(4 * 64 * 4);
  float* pooled = (float*)A((size_t)NG * 64 * 4);
  unsigned* wB   = (unsigned*)A(16384 * 4);  // MFMA B-frag node-MLP weights, 4 layers x 2 mats
  unsigned* ewmf = (unsigned*)A(2048 * 4);   // MFMA-layout f16 edge weights, 4 layers
  float* ebp  = (float*)A(256 * 4);          // padded edge biases, 4 layers
  unsigned* e16 = (unsigned*)A(((size_t)NE + 16) * 32);  // f16 eattr, CSR order, 8 dwords/edge

  hipMemsetAsync(deg, 0, (size_t)NN * 4, stream);
  hipMemsetAsync(bnsq, 0, 4 * 32 * 128 * 4, stream);
  hipMemsetAsync(pooled, 0, (size_t)NG * 64 * 4, stream);
  hipMemsetAsync(csrc + NE, 0, 16 * 4, stream);            // pad: safe src idx for tail chunks
  hipMemsetAsync((char*)e16 + (size_t)NE * 32, 0, 16 * 32, stream);  // pad: clean A-frag tail

  k_wmlp<<<64, 256, 0, stream>>>(l0_w1, w1, l0_w2, w2, wB);
  k_wprep<<<8, 256, 0, stream>>>(l0_ew, l0_eb, ew, eb, ewmf, ebp);
  k_xpad16<<<(NN * 64 + 255) / 256, 256, 0, stream>>>(x_f, xg16);
  k_gstart<<<(NN + 255) / 256, 256, 0, stream>>>(batch, gst);

  k_deg<<<(NE + 255) / 256, 256, 0, stream>>>(edst, deg);
  k_scan1<<<98, 1024, 0, stream>>>(deg, offs, bsum);
  k_scan2<<<1, 128, 0, stream>>>(bsum, 98);
  k_scan3<<<(NN + 255) / 256, 256, 0, stream>>>(offs, bsum, deg, cur, odeg);
  k_fillcast<<<(NE + 255) / 256, 256, 0, stream>>>(esrc, edst, cur, (const float4*)eattr,
                                                   csrc, (uint4*)e16);

  const int rowBlocks = (NN + 63) / 64;
  const int elemBlocks = (NN * 64 + 255) / 256;

  // ---- layer 0 (padded to C=64) ----
  k_layer<<<rowBlocks, 256, 0, stream>>>(csrc, odeg, xg16, e16, ewmf, ebp,
                                         wB, l0_b1, l0_b2, h2, bnsq + 0);
  k_bnfin<<<1, 64, 0, stream>>>(bnsq, bng, bnb, 0, scs, shs);

  // ---- layers 1..3: pre-apply BN(prev)+relu -> f16 gather operand ----
  for (int i = 0; i < 3; i++) {
    k_bnapply<<<elemBlocks, 256, 0, stream>>>(h2, scs + i * 64, shs + i * 64, xg16);
    k_layer<<<rowBlocks, 256, 0, stream>>>(csrc, odeg, xg16,
                                           e16, ewmf + (size_t)(i + 1) * 512, ebp + (i + 1) * 64,
                                           wB + (size_t)(i + 1) * 4096, b1 + (size_t)i * 64,
                                           b2 + (size_t)i * 64, h2, bnsq + (size_t)(i + 1) * 4096);
    k_bnfin<<<1, 64, 0, stream>>>(bnsq, bng, bnb, i + 1, scs, shs);
  }

  // ---- pool (applies BN layer 3) + head ----
  k_pool2<<<NG * 4, 256, 0, stream>>>(h2, scs + 3 * 64, shs + 3 * 64, gst, pooled);
  k_head<<<NG, 128, 0, stream>>>(pooled, gst, hw1, hb1, hw2, hb2, (float*)d_out);
}